// Round 5
// baseline (720.490 us; speedup 1.0000x reference)
//
#include <hip/hip_runtime.h>
#include <cstdint>
#include <cstddef>

// Problem constants (fixed by reference)
#define Bb   8
#define Ss   1024
#define NXx  1024
#define Hh   16
#define HDd  64
#define Mm   (Bb*Ss)      // 8192 rows

typedef __bf16 bf16x8 __attribute__((ext_vector_type(8)));
typedef float  f32x4  __attribute__((ext_vector_type(4)));

// cheap near-RNE fp32->bf16 (2 VALU ops); accuracy headroom is ~4x vs threshold
__device__ __forceinline__ unsigned short f2bf(float f) {
    union { float f; unsigned int u; } v; v.f = f;
    return (unsigned short)((v.u + 0x8000u) >> 16);
}
__device__ __forceinline__ unsigned int f2bf_hi(float f) {   // bf16 in high half
    union { float f; unsigned int u; } v; v.f = f;
    return (v.u + 0x8000u) & 0xffff0000u;
}

// async global->LDS, 16B per lane; LDS dest = wave-uniform base + lane*16
__device__ __forceinline__ void load_lds16(const unsigned short* g, unsigned short* lds_base) {
    __builtin_amdgcn_global_load_lds(
        (const __attribute__((address_space(1))) void*)g,
        (__attribute__((address_space(3))) void*)lds_base, 16, 0, 0);
}

// ---------------- merged prep: casts + weight transposes in one dispatch ----------------
__global__ __launch_bounds__(256) void prep(
    const float* __restrict__ x, const float* __restrict__ query,
    const float* __restrict__ caw, const float* __restrict__ cpw,
    unsigned short* __restrict__ xb, unsigned short* __restrict__ qb,
    unsigned short* __restrict__ Wt, unsigned short* __restrict__ Pt)
{
    __shared__ float tile[32][33];
    const int bid = blockIdx.x;
    const int tid = threadIdx.x;

    if (bid < 16384) {
        const float* in = (bid < 8192) ? x : query;
        unsigned short* out = (bid < 8192) ? xb : qb;
        const int i = ((bid & 8191) * 256 + tid) * 4;
        const float4 v = *(const float4*)(in + i);
        unsigned long long p = (unsigned long long)f2bf(v.x)
            | ((unsigned long long)f2bf(v.y) << 16)
            | ((unsigned long long)f2bf(v.z) << 32)
            | ((unsigned long long)f2bf(v.w) << 48);
        *(unsigned long long*)(out + i) = p;
        return;
    }

    const float* in;
    unsigned short* out;
    int C, t;
    if (bid < 16384 + 3072) { in = caw; out = Wt; C = 3072; t = bid - 16384; }
    else                    { in = cpw; out = Pt; C = 1024; t = bid - 19456; }
    const int ntx = C >> 5;
    const int c0 = (t % ntx) * 32, r0 = (t / ntx) * 32;
    const int tx = tid & 31, ty = tid >> 5;
    for (int i = ty; i < 32; i += 8)
        tile[i][tx] = in[(size_t)(r0 + i) * C + c0 + tx];
    __syncthreads();
    for (int i = ty; i < 32; i += 8)
        out[(size_t)(c0 + i) * 1024 + r0 + tx] = f2bf(tile[tx][i]);
}

// ---------------- 128x128-tile bf16 MFMA GEMM, BK=64 (kept for proj, mode 1) ----------------
__global__ __launch_bounds__(256) void gemm128(
    const unsigned short* __restrict__ Ax,
    const unsigned short* __restrict__ Aq,
    const unsigned short* __restrict__ Bt,
    const float* __restrict__ bias,
    int K, int mode,
    unsigned short* __restrict__ out_q,
    unsigned short* __restrict__ out_k,
    unsigned short* __restrict__ out_v,
    float* __restrict__ out_f)
{
    __shared__ unsigned short smem[16384];    // 32 KB staging; reused for epilogue bounce
    unsigned short (*As)[64] = (unsigned short (*)[64])(smem);
    unsigned short (*Bs)[64] = (unsigned short (*)[64])(smem + 8192);

    const int tid  = threadIdx.x;
    const int w    = tid >> 6;
    const int lane = tid & 63;

    // XCD-aware 2-D supertile swizzle: XCD (n&7) -> 16y x (nx/2)x block
    const int nx   = (mode == 0) ? 24 : 8;
    const int nxh  = nx >> 1;
    const int n    = blockIdx.x;
    const int xcd  = n & 7;
    const int sgrp = n >> 3;
    const int m0   = ((xcd >> 1) * 16 + sgrp / nxh) * 128;
    const int n0   = ((xcd & 1) * nxh + sgrp % nxh) * 128;
    const int region = n0 >> 10;
    const unsigned short* A = (mode == 0 && region == 0) ? Aq : Ax;

    const int wm   = (w >> 1) * 64;
    const int wn   = (w & 1) * 64;
    const int lrow = lane & 15;
    const int quad = lane >> 4;

    f32x4 acc[4][4] = {};

    // staging: wave w covers rows [w*32, w*32+32) in 4 calls of 8 rows each.
    const int rr   = lane >> 3;
    const int scol = (((lane & 7) ^ (lane >> 3)) << 3);
    const unsigned short* Ag = A  + (size_t)(m0 + w * 32 + rr) * K + scol;
    const unsigned short* Bg = Bt + (size_t)(n0 + w * 32 + rr) * K + scol;
    unsigned short* ldsA = smem + (w * 32) * 64;
    unsigned short* ldsB = smem + 8192 + (w * 32) * 64;

    const int swz = lrow & 7;                 // fragment-read swizzle

    for (int k0 = 0; k0 < K; k0 += 64) {
        __syncthreads();
#pragma unroll
        for (int c = 0; c < 4; ++c) {
            load_lds16(Ag + (size_t)(c * 8) * K + k0, ldsA + c * 512);
            load_lds16(Bg + (size_t)(c * 8) * K + k0, ldsB + c * 512);
        }
        __syncthreads();
#pragma unroll
        for (int kk = 0; kk < 2; ++kk) {
            bf16x8 af[4], bfr[4];
            const int pc = (((kk * 4 + quad) ^ swz) << 3);
#pragma unroll
            for (int i = 0; i < 4; ++i) {
                af[i]  = *(const bf16x8*)&As[wm + i * 16 + lrow][pc];
                bfr[i] = *(const bf16x8*)&Bs[wn + i * 16 + lrow][pc];
            }
#pragma unroll
            for (int i = 0; i < 4; ++i)
#pragma unroll
                for (int j = 0; j < 4; ++j)
                    acc[i][j] = __builtin_amdgcn_mfma_f32_16x16x32_bf16(af[i], bfr[j], acc[i][j], 0, 0, 0);
        }
    }

    __syncthreads();   // all waves done reading As/Bs; safe to reuse smem

    if (mode == 1) {
#pragma unroll
        for (int i = 0; i < 4; ++i)
#pragma unroll
            for (int j = 0; j < 4; ++j) {
                const int ncol = n0 + wn + j * 16 + lrow;
                const float bv = bias[ncol];
#pragma unroll
                for (int r = 0; r < 4; ++r) {
                    const int mrow = m0 + wm + i * 16 + quad * 4 + r;
                    out_f[(size_t)mrow * NXx + ncol] = acc[i][j][r] + bv;
                }
            }
        return;
    }

    unsigned short* ep = smem + w * 2048;     // per-wave 4 KB bounce region

    if (region != 2) {
        unsigned short* outp = (region == 0) ? out_q : out_k;
#pragma unroll
        for (int j = 0; j < 4; ++j) {
            const float bv = bias[n0 + wn + j * 16 + lrow];
#pragma unroll
            for (int i = 0; i < 4; ++i)
#pragma unroll
                for (int r = 0; r < 4; ++r)
                    ep[(i * 16 + quad * 4 + r) * 24 + lrow] = f2bf(acc[i][j][r] + bv);
            // per-wave region: in-wave LDS ordering, no barrier needed
#pragma unroll
            for (int t = 0; t < 2; ++t) {
                const int c    = t * 64 + lane;
                const int row  = c >> 1, ch = (c & 1) * 8;
                const int mrow = m0 + wm + row;
                const int cc   = (n0 + wn + j * 16 + ch) & (NXx - 1);
                const int hh   = cc >> 6, dd = cc & 63;
                const int bh   = (mrow >> 10) * Hh + hh;
                const int ss   = mrow & (Ss - 1);
                *(uint4*)&outp[((size_t)bh * Ss + ss) * HDd + dd] =
                    *(const uint4*)&ep[row * 24 + ch];
            }
        }
    } else {
        // V: bounce transposed [col][row] (stride 72) for contiguous-s wide stores
#pragma unroll
        for (int j = 0; j < 4; ++j) {
            const float bv = bias[n0 + wn + j * 16 + lrow];
#pragma unroll
            for (int i = 0; i < 4; ++i)
#pragma unroll
                for (int r = 0; r < 4; ++r)
                    ep[lrow * 72 + i * 16 + quad * 4 + r] = f2bf(acc[i][j][r] + bv);
#pragma unroll
            for (int t = 0; t < 2; ++t) {
                const int c    = t * 64 + lane;
                const int col  = c >> 3, rc = (c & 7) * 8;
                const int cc   = (n0 + wn + j * 16 + col) & (NXx - 1);
                const int hh   = cc >> 6, dd = cc & 63;
                const int mrow = m0 + wm + rc;
                const int bh   = (mrow >> 10) * Hh + hh;
                const int ss   = mrow & (Ss - 1);
                *(uint4*)&out_v[((size_t)bh * HDd + dd) * Ss + ss] =
                    *(const uint4*)&ep[col * 72 + rc];
            }
        }
    }
}

// ---------------- 256x128-tile QKV GEMM: BK=32, 48KB double-buffer, 3 blocks/CU ----------------
// Supply-rate model: wall = staged_bytes / aggregate rate; rate scales with per-CU
// block concurrency (gemm128: 17.2 B/cyc @ 2-3 blocks, r4: 14.9 @ 2 blocks).
// This round: double-buffer 2x24KB = 48KB -> 3 blocks/CU (launch_bounds(512,6),
// VGPR 60 <= 85 cap), 768 blocks ALL resident = ONE round (zero quantization).
// Depth-1 prefetch per K-tile (32 total): barA | stage t+1 (3 loads/wave) |
// vmcnt(3) | barB | 8x ds_read_b128 + 16 MFMA (own-wave lgkm only, no barrier).
// Stage->consume distance ~1 compute phase (~480 cyc); cross-block skew covers rest.
__global__ __launch_bounds__(512, 6) void gemm256(
    const unsigned short* __restrict__ Ax,
    const unsigned short* __restrict__ Aq,
    const unsigned short* __restrict__ Bt,
    const float* __restrict__ bias,
    unsigned short* __restrict__ out_q,
    unsigned short* __restrict__ out_k,
    unsigned short* __restrict__ out_v)
{
    __shared__ unsigned short lds[24576];   // 48 KB: 2 x (A[256][32]=16KB | B[128][32]=8KB)

    const int tid  = threadIdx.x;
    const int w    = tid >> 6;
    const int lane = tid & 63;
    const int wm   = (w >> 1) * 64;         // 4 M-waves x 64 rows
    const int wn   = (w & 1) * 64;          // 2 N-waves x 64 cols
    const int lrow = lane & 15;
    const int quad = lane >> 4;
    const int ph   = (quad ^ (lrow & 3) ^ (lrow >> 2)) & 3;   // frag-read phys chunk

    // XCD swizzle, ni-fast within XCD: A panel reused by all 12 ni before mi advances
    const int n    = blockIdx.x;
    const int xcd  = n & 7;
    const int sg   = n >> 3;                     // 0..95
    const int mi   = (xcd >> 1) * 8 + sg / 12;   // 0..31
    const int ni   = (xcd & 1) * 12 + sg % 12;   // 0..23
    const int m0   = mi << 8;
    const int n0   = ni << 7;
    const int region = n0 >> 10;            // 0=Q 1=K 2=V (block-uniform, BN=128)
    const unsigned short* A = (region == 0) ? Aq : Ax;

    // staging: one load_lds16 = 16 rows x 32 cols (1KB). lane l -> row l>>2, phys l&3;
    // source logical chunk = (l&3) ^ ((l>>2)&3) ^ ((l>>4)&3)
    const int srow = lane >> 2;                  // 0..15
    const int scol = (((lane & 3) ^ (srow & 3) ^ ((srow >> 2) & 3)) << 3);
    // wave w: A rows w*32+{0,16}, B rows w*16  (per K-tile: 3 loads/wave)
    const unsigned short* pA0 = A  + (size_t)(m0 + w * 32 + srow) * 1024 + scol;
    const unsigned short* pA1 = A  + (size_t)(m0 + w * 32 + 16 + srow) * 1024 + scol;
    const unsigned short* pB0 = Bt + (size_t)(n0 + w * 16 + srow) * 1024 + scol;

    f32x4 acc[4][4] = {};

    // prologue: stage tile 0 -> buf 0
    load_lds16(pA0, lds + w * 1024);
    load_lds16(pA1, lds + w * 1024 + 512);
    load_lds16(pB0, lds + 8192 + w * 512);
    pA0 += 32; pA1 += 32; pB0 += 32;

#pragma unroll 1
    for (int t = 0; t < 32; ++t) {
        __builtin_amdgcn_s_barrier();       // barA: reads(t-1) retired -> buf[(t+1)&1] free
        asm volatile("" ::: "memory");
        if (t < 31) {                       // stage tile t+1
            const int bb = ((t + 1) & 1) * 12288;
            load_lds16(pA0, lds + bb + w * 1024);
            load_lds16(pA1, lds + bb + w * 1024 + 512);
            load_lds16(pB0, lds + bb + 8192 + w * 512);
            pA0 += 32; pA1 += 32; pB0 += 32;
            asm volatile("s_waitcnt vmcnt(3)" ::: "memory");   // retire tile t's 3
        } else {
            asm volatile("s_waitcnt vmcnt(0)" ::: "memory");
        }
        __builtin_amdgcn_s_barrier();       // barB: everyone's tile-t staging retired
        asm volatile("" ::: "memory");

        const int base = (t & 1) * 12288;
        const int rA = base + (wm + lrow) * 32 + ph * 8;
        const int rB = base + 8192 + (wn + lrow) * 32 + ph * 8;
        bf16x8 af[4], bq[4];
#pragma unroll
        for (int i = 0; i < 4; ++i) af[i] = *(const bf16x8*)&lds[rA + i * 512];
#pragma unroll
        for (int j = 0; j < 4; ++j) bq[j] = *(const bf16x8*)&lds[rB + j * 512];
        // no barrier here: compiler's own-wave lgkmcnt gates each MFMA; waves skew
        __builtin_amdgcn_s_setprio(1);
#pragma unroll
        for (int i = 0; i < 4; ++i)
#pragma unroll
            for (int j = 0; j < 4; ++j)
                acc[i][j] = __builtin_amdgcn_mfma_f32_16x16x32_bf16(af[i], bq[j], acc[i][j], 0, 0, 0);
        __builtin_amdgcn_s_setprio(0);
    }

    __syncthreads();   // full drain; safe to reuse LDS for epilogue bounce

    unsigned short* ep = lds + w * 2048;     // per-wave 4 KB bounce region

    if (region != 2) {
        unsigned short* outp = (region == 0) ? out_q : out_k;
#pragma unroll
        for (int j = 0; j < 4; ++j) {
            const float bv = bias[n0 + wn + j * 16 + lrow];
#pragma unroll
            for (int i = 0; i < 4; ++i)
#pragma unroll
                for (int r = 0; r < 4; ++r)
                    ep[(i * 16 + quad * 4 + r) * 24 + lrow] = f2bf(acc[i][j][r] + bv);
            // per-wave region: in-wave LDS ordering, no barrier needed
#pragma unroll
            for (int tt = 0; tt < 2; ++tt) {
                const int c    = tt * 64 + lane;
                const int row  = c >> 1, ch = (c & 1) * 8;
                const int mrow = m0 + wm + row;
                const int cc   = (n0 + wn + j * 16 + ch) & (NXx - 1);
                const int hh   = cc >> 6, dd = cc & 63;
                const int bh   = (mrow >> 10) * Hh + hh;
                const int ss   = mrow & (Ss - 1);
                *(uint4*)&outp[((size_t)bh * Ss + ss) * HDd + dd] =
                    *(const uint4*)&ep[row * 24 + ch];
            }
        }
    } else {
        // V: bounce transposed [col][row] (stride 72) for contiguous-s wide stores
#pragma unroll
        for (int j = 0; j < 4; ++j) {
            const float bv = bias[n0 + wn + j * 16 + lrow];
#pragma unroll
            for (int i = 0; i < 4; ++i)
#pragma unroll
                for (int r = 0; r < 4; ++r)
                    ep[lrow * 72 + i * 16 + quad * 4 + r] = f2bf(acc[i][j][r] + bv);
#pragma unroll
            for (int tt = 0; tt < 2; ++tt) {
                const int c    = tt * 64 + lane;
                const int col  = c >> 3, rc = (c & 7) * 8;
                const int cc   = (n0 + wn + j * 16 + col) & (NXx - 1);
                const int hh   = cc >> 6, dd = cc & 63;
                const int mrow = m0 + wm + rc;
                const int bh   = (mrow >> 10) * Hh + hh;
                const int ss   = mrow & (Ss - 1);
                *(uint4*)&out_v[((size_t)bh * HDd + dd) * Ss + ss] =
                    *(const uint4*)&ep[col * 72 + rc];
            }
        }
    }
}

// ---------------- flash-style causal attention, S^T formulation, PIPELINED ----------------
// Double-buffered Ks/Vs; flattened 18-iteration loop over both q-supertile halves
// (nkt0 = 2*pr+2 is block-uniform -> barriers uniform). Per iter: barA | stage it+1
// (4 loads) | vmcnt(4) | barB | compute it (skip if fully masked, wave-uniform).
// Removes the per-iteration vmcnt(0) serial drain the old sync;load;sync paid.
// Half transition at it==nkt0: write half-A output (regs only), reload aq, reset O/l.
__global__ __launch_bounds__(256) void flash_attn(
    const unsigned short* __restrict__ Qh,
    const unsigned short* __restrict__ Kh,
    const unsigned short* __restrict__ Vt,
    unsigned short* __restrict__ about)
{
    __shared__ unsigned short Ks[2][64][64];     // phys_chunk = log ^ (row&7)
    __shared__ unsigned short Vs[2][64][64];
    __shared__ unsigned short Pl[4][32][72];     // per-wave P, [q][key], stride 144B

    const int tid  = threadIdx.x;
    const int w    = tid >> 6;
    const int lane = tid & 63;
    const int bh   = blockIdx.x & 127;
    const int pr   = blockIdx.x >> 7;
    const int b    = bh >> 4, h = bh & 15;
    const int lrow = lane & 15;
    const int quad = lane >> 4;

    const unsigned short* Qb = Qh + (size_t)bh * Ss * HDd;
    const unsigned short* Kb = Kh + (size_t)bh * Ss * HDd;
    const unsigned short* Vb = Vt + (size_t)bh * HDd * Ss;

    // staging: 2 calls of 8 rows per matrix per wave; source col permuted
    const int sr = lane >> 3;
    const int lc = (((lane & 7) ^ (lane >> 3)) << 3);

    const int swz = lrow & 7;
    const int ca = ((quad ^ swz) << 3);            // k/d 0..31
    const int cb = (((4 + quad) ^ swz) << 3);      // k/d 32..63

    const int nkt0 = 2 * pr + 2;                   // half-A iterations; total = 18
    int qt = pr;
    int qw = qt * 128 + w * 32;                    // wave's first q row

    bf16x8 aq[2][2];
#pragma unroll
    for (int g = 0; g < 2; ++g)
#pragma unroll
        for (int c = 0; c < 2; ++c)
            aq[g][c] = *(const bf16x8*)(Qb + (size_t)(qw + g * 16 + lrow) * HDd + c * 32 + quad * 8);

    f32x4 O[2][4] = {};
    float lsum[2] = { 0.f, 0.f };

    // prologue: stage it=0 (k0=0) into buf 0
    load_lds16(Kb + (size_t)(w * 16 + sr) * HDd + lc,     &Ks[0][w * 16][0]);
    load_lds16(Kb + (size_t)(w * 16 + sr + 8) * HDd + lc, &Ks[0][w * 16 + 8][0]);
    load_lds16(Vb + (size_t)(w * 16 + sr) * Ss + lc,      &Vs[0][w * 16][0]);
    load_lds16(Vb + (size_t)(w * 16 + sr + 8) * Ss + lc,  &Vs[0][w * 16 + 8][0]);

#pragma unroll 1
    for (int it = 0; it < 18; ++it) {
        __builtin_amdgcn_s_barrier();   // barA: all reads of buf[(it+1)&1] (iter it-1) done
        asm volatile("" ::: "memory");
        if (it < 17) {
            const int itn  = it + 1;
            const int bsel = itn & 1;
            const int k0n  = (itn >= nkt0 ? itn - nkt0 : itn) * 64;
            load_lds16(Kb + (size_t)(k0n + w * 16 + sr) * HDd + lc,     &Ks[bsel][w * 16][0]);
            load_lds16(Kb + (size_t)(k0n + w * 16 + sr + 8) * HDd + lc, &Ks[bsel][w * 16 + 8][0]);
            load_lds16(Vb + (size_t)(w * 16 + sr) * Ss + k0n + lc,      &Vs[bsel][w * 16][0]);
            load_lds16(Vb + (size_t)(w * 16 + sr + 8) * Ss + k0n + lc,  &Vs[bsel][w * 16 + 8][0]);
            asm volatile("s_waitcnt vmcnt(4)" ::: "memory");   // retire iter-it's 4
        } else {
            asm volatile("s_waitcnt vmcnt(0)" ::: "memory");
        }
        __builtin_amdgcn_s_barrier();   // barB: everyone's iter-it staging retired
        asm volatile("" ::: "memory");

        if (it == nkt0) {
            // finish half A: quad-reduce l, normalize, store (registers + shfl only)
#pragma unroll
            for (int g = 0; g < 2; ++g) {
                float l = lsum[g];
                l += __shfl_xor(l, 16);
                l += __shfl_xor(l, 32);
                const float inv = 1.0f / l;
#pragma unroll
                for (int r = 0; r < 4; ++r) {
                    const float invr = __shfl(inv, quad * 4 + r);
                    const int q = qw + g * 16 + quad * 4 + r;
                    const size_t base = ((size_t)b * Ss + q) * NXx + h * HDd;
#pragma unroll
                    for (int f = 0; f < 4; ++f)
                        about[base + f * 16 + lrow] = f2bf(O[g][f][r] * invr);
                }
            }
            // switch to half B
            qt = 7 - pr;
            qw = qt * 128 + w * 32;
#pragma unroll
            for (int g = 0; g < 2; ++g)
#pragma unroll
                for (int c = 0; c < 2; ++c)
                    aq[g][c] = *(const bf16x8*)(Qb + (size_t)(qw + g * 16 + lrow) * HDd + c * 32 + quad * 8);
#pragma unroll
            for (int g = 0; g < 2; ++g) {
                lsum[g] = 0.f;
#pragma unroll
                for (int f = 0; f < 4; ++f) O[g][f] = (f32x4){0.f, 0.f, 0.f, 0.f};
            }
        }

        const int k0 = (it >= nkt0 ? it - nkt0 : it) * 64;
        if (k0 > qw + 31) continue;            // fully masked (wave-uniform)
        const int bs = it & 1;

        // S^T = K·Q^T: D[key = j*16+quad*4+r][q = g*16+lrow]
        f32x4 st[2][4] = {};
#pragma unroll
        for (int j = 0; j < 4; ++j) {
            const bf16x8 kf0 = *(const bf16x8*)&Ks[bs][j * 16 + lrow][ca];
            const bf16x8 kf1 = *(const bf16x8*)&Ks[bs][j * 16 + lrow][cb];
            st[0][j] = __builtin_amdgcn_mfma_f32_16x16x32_bf16(kf0, aq[0][0], st[0][j], 0, 0, 0);
            st[0][j] = __builtin_amdgcn_mfma_f32_16x16x32_bf16(kf1, aq[0][1], st[0][j], 0, 0, 0);
            st[1][j] = __builtin_amdgcn_mfma_f32_16x16x32_bf16(kf0, aq[1][0], st[1][j], 0, 0, 0);
            st[1][j] = __builtin_amdgcn_mfma_f32_16x16x32_bf16(kf1, aq[1][1], st[1][j], 0, 0, 0);
        }

        const bool needMask = (k0 + 63 > qw);  // wave-uniform
#pragma unroll
        for (int g = 0; g < 2; ++g) {
            const int qg = qw + g * 16 + lrow;  // this lane's q row
#pragma unroll
            for (int j = 0; j < 4; ++j) {
                const int kbase = k0 + j * 16 + quad * 4;
                float e0 = __expf(st[g][j][0] * 0.125f);
                float e1 = __expf(st[g][j][1] * 0.125f);
                float e2 = __expf(st[g][j][2] * 0.125f);
                float e3 = __expf(st[g][j][3] * 0.125f);
                if (needMask) {
                    if (kbase     > qg) e0 = 0.f;
                    if (kbase + 1 > qg) e1 = 0.f;
                    if (kbase + 2 > qg) e2 = 0.f;
                    if (kbase + 3 > qg) e3 = 0.f;
                }
                lsum[g] += (e0 + e1) + (e2 + e3);
                uint2 pk;
                pk.x = (unsigned)f2bf(e0) | f2bf_hi(e1);
                pk.y = (unsigned)f2bf(e2) | f2bf_hi(e3);
                *(uint2*)&Pl[w][g * 16 + lrow][j * 16 + quad * 4] = pk;
            }
        }
        // Pl[w] is per-wave: in-wave DS ordering suffices, no barrier

        bf16x8 ap[2][2];
#pragma unroll
        for (int g = 0; g < 2; ++g)
#pragma unroll
            for (int c = 0; c < 2; ++c)
                ap[g][c] = *(const bf16x8*)&Pl[w][g * 16 + lrow][c * 32 + quad * 8];
#pragma unroll
        for (int f = 0; f < 4; ++f) {
            const bf16x8 vf0 = *(const bf16x8*)&Vs[bs][f * 16 + lrow][ca];
            const bf16x8 vf1 = *(const bf16x8*)&Vs[bs][f * 16 + lrow][cb];
            O[0][f] = __builtin_amdgcn_mfma_f32_16x16x32_bf16(ap[0][0], vf0, O[0][f], 0, 0, 0);
            O[0][f] = __builtin_amdgcn_mfma_f32_16x16x32_bf16(ap[0][1], vf1, O[0][f], 0, 0, 0);
            O[1][f] = __builtin_amdgcn_mfma_f32_16x16x32_bf16(ap[1][0], vf0, O[1][f], 0, 0, 0);
            O[1][f] = __builtin_amdgcn_mfma_f32_16x16x32_bf16(ap[1][1], vf1, O[1][f], 0, 0, 0);
        }
    }

    // final epilogue: half B
#pragma unroll
    for (int g = 0; g < 2; ++g) {
        float l = lsum[g];
        l += __shfl_xor(l, 16);
        l += __shfl_xor(l, 32);
        const float inv = 1.0f / l;
#pragma unroll
        for (int r = 0; r < 4; ++r) {
            const float invr = __shfl(inv, quad * 4 + r);
            const int q = qw + g * 16 + quad * 4 + r;
            const size_t base = ((size_t)b * Ss + q) * NXx + h * HDd;
#pragma unroll
            for (int f = 0; f < 4; ++f)
                about[base + f * 16 + lrow] = f2bf(O[g][f][r] * invr);
        }
    }
}

// ---------------- launch ----------------
extern "C" void kernel_launch(void* const* d_in, const int* in_sizes, int n_in,
                              void* d_out, int out_size, void* d_ws, size_t ws_size,
                              hipStream_t stream) {
    const float* x        = (const float*)d_in[0];
    const float* query    = (const float*)d_in[1];
    const float* c_attn_w = (const float*)d_in[2];
    const float* c_attn_b = (const float*)d_in[3];
    const float* c_proj_w = (const float*)d_in[4];
    const float* c_proj_b = (const float*)d_in[5];
    float* out = (float*)d_out;

    const size_t nTok = (size_t)Mm * NXx;          // 8388608
    char* ws = (char*)d_ws;
    unsigned short* xb    = (unsigned short*)ws;                 ws += nTok * 2;
    unsigned short* qb    = (unsigned short*)ws;                 ws += nTok * 2;
    unsigned short* Wt    = (unsigned short*)ws;                 ws += (size_t)3 * NXx * NXx * 2;  // [3072][1024]
    unsigned short* Pt    = (unsigned short*)ws;                 ws += (size_t)NXx * NXx * 2;      // [1024][1024]
    unsigned short* Qh    = (unsigned short*)ws;                 ws += nTok * 2;
    unsigned short* Kh    = (unsigned short*)ws;                 ws += nTok * 2;
    unsigned short* Vt    = (unsigned short*)ws;                 ws += nTok * 2;
    unsigned short* about = (unsigned short*)ws;                 ws += nTok * 2;
    if ((size_t)(ws - (char*)d_ws) > ws_size) return;

    // merged prep: casts + transposes
    prep<<<20480, 256, 0, stream>>>(x, query, c_attn_w, c_proj_w, xb, qb, Wt, Pt);

    // QKV: M=8192, N=3072, K=1024 — 256x128 tiles, BK=32, 3 blocks/CU, all resident
    gemm256<<<768, 512, 0, stream>>>(xb, qb, Wt, c_attn_b, Qh, Kh, Vt);

    // causal flash attention (pipelined double-buffer staging)
    flash_attn<<<512, 256, 0, stream>>>(Qh, Kh, Vt, about);

    // output projection: M=8192, N=1024, K=1024 -> fp32 out
    gemm128<<<dim3(8 * 64), 256, 0, stream>>>(about, nullptr, Pt, c_proj_b, NXx, 1,
                                              nullptr, nullptr, nullptr, out);
}

// Round 6
// 261.137 us; speedup vs baseline: 2.7591x; 2.7591x over previous
//
#include <hip/hip_runtime.h>
#include <cstdint>
#include <cstddef>

// Problem constants (fixed by reference)
#define Bb   8
#define Ss   1024
#define NXx  1024
#define Hh   16
#define HDd  64
#define Mm   (Bb*Ss)      // 8192 rows

typedef __bf16 bf16x8 __attribute__((ext_vector_type(8)));
typedef float  f32x4  __attribute__((ext_vector_type(4)));

// cheap near-RNE fp32->bf16 (2 VALU ops); accuracy headroom is ~4x vs threshold
__device__ __forceinline__ unsigned short f2bf(float f) {
    union { float f; unsigned int u; } v; v.f = f;
    return (unsigned short)((v.u + 0x8000u) >> 16);
}
__device__ __forceinline__ unsigned int f2bf_hi(float f) {   // bf16 in high half
    union { float f; unsigned int u; } v; v.f = f;
    return (v.u + 0x8000u) & 0xffff0000u;
}

// async global->LDS, 16B per lane; LDS dest = wave-uniform base + lane*16
__device__ __forceinline__ void load_lds16(const unsigned short* g, unsigned short* lds_base) {
    __builtin_amdgcn_global_load_lds(
        (const __attribute__((address_space(1))) void*)g,
        (__attribute__((address_space(3))) void*)lds_base, 16, 0, 0);
}

// ---------------- merged prep: casts + weight transposes in one dispatch ----------------
__global__ __launch_bounds__(256) void prep(
    const float* __restrict__ x, const float* __restrict__ query,
    const float* __restrict__ caw, const float* __restrict__ cpw,
    unsigned short* __restrict__ xb, unsigned short* __restrict__ qb,
    unsigned short* __restrict__ Wt, unsigned short* __restrict__ Pt)
{
    __shared__ float tile[32][33];
    const int bid = blockIdx.x;
    const int tid = threadIdx.x;

    if (bid < 16384) {
        const float* in = (bid < 8192) ? x : query;
        unsigned short* out = (bid < 8192) ? xb : qb;
        const int i = ((bid & 8191) * 256 + tid) * 4;
        const float4 v = *(const float4*)(in + i);
        unsigned long long p = (unsigned long long)f2bf(v.x)
            | ((unsigned long long)f2bf(v.y) << 16)
            | ((unsigned long long)f2bf(v.z) << 32)
            | ((unsigned long long)f2bf(v.w) << 48);
        *(unsigned long long*)(out + i) = p;
        return;
    }

    const float* in;
    unsigned short* out;
    int C, t;
    if (bid < 16384 + 3072) { in = caw; out = Wt; C = 3072; t = bid - 16384; }
    else                    { in = cpw; out = Pt; C = 1024; t = bid - 19456; }
    const int ntx = C >> 5;
    const int c0 = (t % ntx) * 32, r0 = (t / ntx) * 32;
    const int tx = tid & 31, ty = tid >> 5;
    for (int i = ty; i < 32; i += 8)
        tile[i][tx] = in[(size_t)(r0 + i) * C + c0 + tx];
    __syncthreads();
    for (int i = ty; i < 32; i += 8)
        out[(size_t)(c0 + i) * 1024 + r0 + tx] = f2bf(tile[tx][i]);
}

// ---------------- 256x128-tile GEMM: BK=32, 72KB triple-buffer, depth-2 prefetch ----------------
// Round-4 verified config (64.6 us QKV, VGPR 60, no spill). launch_bounds(512,4):
// VGPR cap 128 >= ~110 live need — do NOT raise min-waves (r5: (512,6) capped at 85,
// spilled acc to scratch, FETCH 51MB->898MB, 531us).
// 8 waves 4Mx2N, wave tile 64x64. Per K-tile (32): barA | stage t+2 (3 loads/wave) |
// vmcnt(6) | barB | 8x ds_read_b128 + 16 MFMA (own-wave lgkm only, no barrier after barB).
// mode 0: QKV, 768 blocks (exact 3 rounds at 2 blocks/CU), region-pure BN=128,
//         scatter epilogue to Qh/Kh/Vt. mode 1: proj, 256 blocks (exact 1 round),
//         direct fp32 out_f epilogue (gemm128's verified mode-1 index algebra).
__global__ __launch_bounds__(512, 4) void gemm256(
    const unsigned short* __restrict__ Ax,
    const unsigned short* __restrict__ Aq,
    const unsigned short* __restrict__ Bt,
    const float* __restrict__ bias,
    int mode,
    unsigned short* __restrict__ out_q,
    unsigned short* __restrict__ out_k,
    unsigned short* __restrict__ out_v,
    float* __restrict__ out_f)
{
    __shared__ unsigned short lds[36864];   // 72 KB: 3 x (A[256][32]=16KB | B[128][32]=8KB)

    const int tid  = threadIdx.x;
    const int w    = tid >> 6;
    const int lane = tid & 63;
    const int wm   = (w >> 1) * 64;         // 4 M-waves x 64 rows
    const int wn   = (w & 1) * 64;          // 2 N-waves x 64 cols
    const int lrow = lane & 15;
    const int quad = lane >> 4;
    const int ph   = (quad ^ (lrow & 3) ^ (lrow >> 2)) & 3;   // frag-read phys chunk

    // XCD swizzle, ni-fast within XCD (A panel L2 reuse). mode0: 768=8x96, 8(mi)x12(ni)
    // per XCD-pair region; mode1: 256=8x32, 8(mi)x4(ni).
    const int nph  = (mode == 0) ? 12 : 4;       // ni per XCD-half
    const int n    = blockIdx.x;
    const int xcd  = n & 7;
    const int sg   = n >> 3;
    const int mi   = (xcd >> 1) * 8 + sg / nph;  // 0..31
    const int ni   = (xcd & 1) * nph + sg % nph;
    const int m0   = mi << 8;
    const int n0   = ni << 7;
    const int region = n0 >> 10;            // mode0: 0=Q 1=K 2=V (block-uniform, BN=128)
    const unsigned short* A = (mode == 0 && region == 0) ? Aq : Ax;

    // staging: one load_lds16 = 16 rows x 32 cols (1KB). lane l -> row l>>2, phys l&3;
    // source logical chunk = (l&3) ^ ((l>>2)&3) ^ ((l>>4)&3)
    const int srow = lane >> 2;                  // 0..15
    const int scol = (((lane & 3) ^ (srow & 3) ^ ((srow >> 2) & 3)) << 3);
    // wave w: A rows w*32+{0,16}, B rows w*16  (per K-tile: 3 loads/wave)
    const unsigned short* pA0 = A  + (size_t)(m0 + w * 32 + srow) * 1024 + scol;
    const unsigned short* pA1 = A  + (size_t)(m0 + w * 32 + 16 + srow) * 1024 + scol;
    const unsigned short* pB0 = Bt + (size_t)(n0 + w * 16 + srow) * 1024 + scol;

    f32x4 acc[4][4] = {};

    // prologue: stage tiles 0,1 into bufs 0,1 (6 loads in flight)
#pragma unroll
    for (int p = 0; p < 2; ++p) {
        const int bb = p * 12288;
        load_lds16(pA0, lds + bb + w * 1024);
        load_lds16(pA1, lds + bb + w * 1024 + 512);
        load_lds16(pB0, lds + bb + 8192 + w * 512);
        pA0 += 32; pA1 += 32; pB0 += 32;
    }

    int cbuf = 0;   // buffer holding tile t
    int sbuf = 2;   // buffer to stage tile t+2 into
#pragma unroll 1
    for (int t = 0; t < 32; ++t) {
        __builtin_amdgcn_s_barrier();       // barA: all reads(t-1) retired -> sbuf free
        asm volatile("" ::: "memory");
        if (t <= 29) {                      // stage tile t+2
            const int bb = sbuf * 12288;
            load_lds16(pA0, lds + bb + w * 1024);
            load_lds16(pA1, lds + bb + w * 1024 + 512);
            load_lds16(pB0, lds + bb + 8192 + w * 512);
            pA0 += 32; pA1 += 32; pB0 += 32;
            asm volatile("s_waitcnt vmcnt(6)" ::: "memory");   // retire tile t's 3
        } else if (t == 30) {
            asm volatile("s_waitcnt vmcnt(3)" ::: "memory");
        } else {
            asm volatile("s_waitcnt vmcnt(0)" ::: "memory");
        }
        __builtin_amdgcn_s_barrier();       // barB: everyone's tile-t staging retired
        asm volatile("" ::: "memory");

        const int rA = cbuf * 12288 + (wm + lrow) * 32 + ph * 8;
        const int rB = cbuf * 12288 + 8192 + (wn + lrow) * 32 + ph * 8;
        bf16x8 af[4], bq[4];
#pragma unroll
        for (int i = 0; i < 4; ++i) af[i] = *(const bf16x8*)&lds[rA + i * 512];
#pragma unroll
        for (int j = 0; j < 4; ++j) bq[j] = *(const bf16x8*)&lds[rB + j * 512];
        // no barrier here: compiler's own-wave lgkmcnt gates each MFMA; waves skew
        __builtin_amdgcn_s_setprio(1);
#pragma unroll
        for (int i = 0; i < 4; ++i)
#pragma unroll
            for (int j = 0; j < 4; ++j)
                acc[i][j] = __builtin_amdgcn_mfma_f32_16x16x32_bf16(af[i], bq[j], acc[i][j], 0, 0, 0);
        __builtin_amdgcn_s_setprio(0);

        cbuf = (cbuf == 2) ? 0 : cbuf + 1;
        sbuf = (sbuf == 2) ? 0 : sbuf + 1;
    }

    if (mode == 1) {
        // proj epilogue: direct fp32 stores (gemm128 mode-1 algebra, same wm/wn/quad/lrow)
#pragma unroll
        for (int i = 0; i < 4; ++i)
#pragma unroll
            for (int j = 0; j < 4; ++j) {
                const int ncol = n0 + wn + j * 16 + lrow;
                const float bv = bias[ncol];
#pragma unroll
                for (int r = 0; r < 4; ++r) {
                    const int mrow = m0 + wm + i * 16 + quad * 4 + r;
                    out_f[(size_t)mrow * NXx + ncol] = acc[i][j][r] + bv;
                }
            }
        return;
    }

    __syncthreads();   // full drain; safe to reuse LDS for epilogue bounce

    unsigned short* ep = lds + w * 2048;     // per-wave 4 KB bounce region

    if (region != 2) {
        unsigned short* outp = (region == 0) ? out_q : out_k;
#pragma unroll
        for (int j = 0; j < 4; ++j) {
            const float bv = bias[n0 + wn + j * 16 + lrow];
#pragma unroll
            for (int i = 0; i < 4; ++i)
#pragma unroll
                for (int r = 0; r < 4; ++r)
                    ep[(i * 16 + quad * 4 + r) * 24 + lrow] = f2bf(acc[i][j][r] + bv);
            // per-wave region: in-wave LDS ordering, no barrier needed
#pragma unroll
            for (int tt = 0; tt < 2; ++tt) {
                const int c    = tt * 64 + lane;
                const int row  = c >> 1, ch = (c & 1) * 8;
                const int mrow = m0 + wm + row;
                const int cc   = (n0 + wn + j * 16 + ch) & (NXx - 1);
                const int hh   = cc >> 6, dd = cc & 63;
                const int bh   = (mrow >> 10) * Hh + hh;
                const int ss   = mrow & (Ss - 1);
                *(uint4*)&outp[((size_t)bh * Ss + ss) * HDd + dd] =
                    *(const uint4*)&ep[row * 24 + ch];
            }
        }
    } else {
        // V: bounce transposed [col][row] (stride 72) for contiguous-s wide stores
#pragma unroll
        for (int j = 0; j < 4; ++j) {
            const float bv = bias[n0 + wn + j * 16 + lrow];
#pragma unroll
            for (int i = 0; i < 4; ++i)
#pragma unroll
                for (int r = 0; r < 4; ++r)
                    ep[lrow * 72 + i * 16 + quad * 4 + r] = f2bf(acc[i][j][r] + bv);
#pragma unroll
            for (int tt = 0; tt < 2; ++tt) {
                const int c    = tt * 64 + lane;
                const int col  = c >> 3, rc = (c & 7) * 8;
                const int cc   = (n0 + wn + j * 16 + col) & (NXx - 1);
                const int hh   = cc >> 6, dd = cc & 63;
                const int mrow = m0 + wm + rc;
                const int bh   = (mrow >> 10) * Hh + hh;
                const int ss   = mrow & (Ss - 1);
                *(uint4*)&out_v[((size_t)bh * HDd + dd) * Ss + ss] =
                    *(const uint4*)&ep[col * 72 + rc];
            }
        }
    }
}

// ---------------- flash-style causal attention, S^T formulation, PIPELINED ----------------
// Double-buffered Ks/Vs; flattened 18-iteration loop over both q-supertile halves
// (nkt0 = 2*pr+2 is block-uniform -> barriers uniform). Per iter: barA | stage it+1
// (4 loads) | vmcnt(4) | barB | compute it (skip if fully masked, wave-uniform).
// Removes the per-iteration vmcnt(0) serial drain (measured ~5us vs unpipelined).
// Half transition at it==nkt0: write half-A output (regs only), reload aq, reset O/l.
__global__ __launch_bounds__(256) void flash_attn(
    const unsigned short* __restrict__ Qh,
    const unsigned short* __restrict__ Kh,
    const unsigned short* __restrict__ Vt,
    unsigned short* __restrict__ about)
{
    __shared__ unsigned short Ks[2][64][64];     // phys_chunk = log ^ (row&7)
    __shared__ unsigned short Vs[2][64][64];
    __shared__ unsigned short Pl[4][32][72];     // per-wave P, [q][key], stride 144B

    const int tid  = threadIdx.x;
    const int w    = tid >> 6;
    const int lane = tid & 63;
    const int bh   = blockIdx.x & 127;
    const int pr   = blockIdx.x >> 7;
    const int b    = bh >> 4, h = bh & 15;
    const int lrow = lane & 15;
    const int quad = lane >> 4;

    const unsigned short* Qb = Qh + (size_t)bh * Ss * HDd;
    const unsigned short* Kb = Kh + (size_t)bh * Ss * HDd;
    const unsigned short* Vb = Vt + (size_t)bh * HDd * Ss;

    // staging: 2 calls of 8 rows per matrix per wave; source col permuted
    const int sr = lane >> 3;
    const int lc = (((lane & 7) ^ (lane >> 3)) << 3);

    const int swz = lrow & 7;
    const int ca = ((quad ^ swz) << 3);            // k/d 0..31
    const int cb = (((4 + quad) ^ swz) << 3);      // k/d 32..63

    const int nkt0 = 2 * pr + 2;                   // half-A iterations; total = 18
    int qt = pr;
    int qw = qt * 128 + w * 32;                    // wave's first q row

    bf16x8 aq[2][2];
#pragma unroll
    for (int g = 0; g < 2; ++g)
#pragma unroll
        for (int c = 0; c < 2; ++c)
            aq[g][c] = *(const bf16x8*)(Qb + (size_t)(qw + g * 16 + lrow) * HDd + c * 32 + quad * 8);

    f32x4 O[2][4] = {};
    float lsum[2] = { 0.f, 0.f };

    // prologue: stage it=0 (k0=0) into buf 0
    load_lds16(Kb + (size_t)(w * 16 + sr) * HDd + lc,     &Ks[0][w * 16][0]);
    load_lds16(Kb + (size_t)(w * 16 + sr + 8) * HDd + lc, &Ks[0][w * 16 + 8][0]);
    load_lds16(Vb + (size_t)(w * 16 + sr) * Ss + lc,      &Vs[0][w * 16][0]);
    load_lds16(Vb + (size_t)(w * 16 + sr + 8) * Ss + lc,  &Vs[0][w * 16 + 8][0]);

#pragma unroll 1
    for (int it = 0; it < 18; ++it) {
        __builtin_amdgcn_s_barrier();   // barA: all reads of buf[(it+1)&1] (iter it-1) done
        asm volatile("" ::: "memory");
        if (it < 17) {
            const int itn  = it + 1;
            const int bsel = itn & 1;
            const int k0n  = (itn >= nkt0 ? itn - nkt0 : itn) * 64;
            load_lds16(Kb + (size_t)(k0n + w * 16 + sr) * HDd + lc,     &Ks[bsel][w * 16][0]);
            load_lds16(Kb + (size_t)(k0n + w * 16 + sr + 8) * HDd + lc, &Ks[bsel][w * 16 + 8][0]);
            load_lds16(Vb + (size_t)(w * 16 + sr) * Ss + k0n + lc,      &Vs[bsel][w * 16][0]);
            load_lds16(Vb + (size_t)(w * 16 + sr + 8) * Ss + k0n + lc,  &Vs[bsel][w * 16 + 8][0]);
            asm volatile("s_waitcnt vmcnt(4)" ::: "memory");   // retire iter-it's 4
        } else {
            asm volatile("s_waitcnt vmcnt(0)" ::: "memory");
        }
        __builtin_amdgcn_s_barrier();   // barB: everyone's iter-it staging retired
        asm volatile("" ::: "memory");

        if (it == nkt0) {
            // finish half A: quad-reduce l, normalize, store (registers + shfl only)
#pragma unroll
            for (int g = 0; g < 2; ++g) {
                float l = lsum[g];
                l += __shfl_xor(l, 16);
                l += __shfl_xor(l, 32);
                const float inv = 1.0f / l;
#pragma unroll
                for (int r = 0; r < 4; ++r) {
                    const float invr = __shfl(inv, quad * 4 + r);
                    const int q = qw + g * 16 + quad * 4 + r;
                    const size_t base = ((size_t)b * Ss + q) * NXx + h * HDd;
#pragma unroll
                    for (int f = 0; f < 4; ++f)
                        about[base + f * 16 + lrow] = f2bf(O[g][f][r] * invr);
                }
            }
            // switch to half B
            qt = 7 - pr;
            qw = qt * 128 + w * 32;
#pragma unroll
            for (int g = 0; g < 2; ++g)
#pragma unroll
                for (int c = 0; c < 2; ++c)
                    aq[g][c] = *(const bf16x8*)(Qb + (size_t)(qw + g * 16 + lrow) * HDd + c * 32 + quad * 8);
#pragma unroll
            for (int g = 0; g < 2; ++g) {
                lsum[g] = 0.f;
#pragma unroll
                for (int f = 0; f < 4; ++f) O[g][f] = (f32x4){0.f, 0.f, 0.f, 0.f};
            }
        }

        const int k0 = (it >= nkt0 ? it - nkt0 : it) * 64;
        if (k0 > qw + 31) continue;            // fully masked (wave-uniform)
        const int bs = it & 1;

        // S^T = K·Q^T: D[key = j*16+quad*4+r][q = g*16+lrow]
        f32x4 st[2][4] = {};
#pragma unroll
        for (int j = 0; j < 4; ++j) {
            const bf16x8 kf0 = *(const bf16x8*)&Ks[bs][j * 16 + lrow][ca];
            const bf16x8 kf1 = *(const bf16x8*)&Ks[bs][j * 16 + lrow][cb];
            st[0][j] = __builtin_amdgcn_mfma_f32_16x16x32_bf16(kf0, aq[0][0], st[0][j], 0, 0, 0);
            st[0][j] = __builtin_amdgcn_mfma_f32_16x16x32_bf16(kf1, aq[0][1], st[0][j], 0, 0, 0);
            st[1][j] = __builtin_amdgcn_mfma_f32_16x16x32_bf16(kf0, aq[1][0], st[1][j], 0, 0, 0);
            st[1][j] = __builtin_amdgcn_mfma_f32_16x16x32_bf16(kf1, aq[1][1], st[1][j], 0, 0, 0);
        }

        const bool needMask = (k0 + 63 > qw);  // wave-uniform
#pragma unroll
        for (int g = 0; g < 2; ++g) {
            const int qg = qw + g * 16 + lrow;  // this lane's q row
#pragma unroll
            for (int j = 0; j < 4; ++j) {
                const int kbase = k0 + j * 16 + quad * 4;
                float e0 = __expf(st[g][j][0] * 0.125f);
                float e1 = __expf(st[g][j][1] * 0.125f);
                float e2 = __expf(st[g][j][2] * 0.125f);
                float e3 = __expf(st[g][j][3] * 0.125f);
                if (needMask) {
                    if (kbase     > qg) e0 = 0.f;
                    if (kbase + 1 > qg) e1 = 0.f;
                    if (kbase + 2 > qg) e2 = 0.f;
                    if (kbase + 3 > qg) e3 = 0.f;
                }
                lsum[g] += (e0 + e1) + (e2 + e3);
                uint2 pk;
                pk.x = (unsigned)f2bf(e0) | f2bf_hi(e1);
                pk.y = (unsigned)f2bf(e2) | f2bf_hi(e3);
                *(uint2*)&Pl[w][g * 16 + lrow][j * 16 + quad * 4] = pk;
            }
        }
        // Pl[w] is per-wave: in-wave DS ordering suffices, no barrier

        bf16x8 ap[2][2];
#pragma unroll
        for (int g = 0; g < 2; ++g)
#pragma unroll
            for (int c = 0; c < 2; ++c)
                ap[g][c] = *(const bf16x8*)&Pl[w][g * 16 + lrow][c * 32 + quad * 8];
#pragma unroll
        for (int f = 0; f < 4; ++f) {
            const bf16x8 vf0 = *(const bf16x8*)&Vs[bs][f * 16 + lrow][ca];
            const bf16x8 vf1 = *(const bf16x8*)&Vs[bs][f * 16 + lrow][cb];
            O[0][f] = __builtin_amdgcn_mfma_f32_16x16x32_bf16(ap[0][0], vf0, O[0][f], 0, 0, 0);
            O[0][f] = __builtin_amdgcn_mfma_f32_16x16x32_bf16(ap[0][1], vf1, O[0][f], 0, 0, 0);
            O[1][f] = __builtin_amdgcn_mfma_f32_16x16x32_bf16(ap[1][0], vf0, O[1][f], 0, 0, 0);
            O[1][f] = __builtin_amdgcn_mfma_f32_16x16x32_bf16(ap[1][1], vf1, O[1][f], 0, 0, 0);
        }
    }

    // final epilogue: half B
#pragma unroll
    for (int g = 0; g < 2; ++g) {
        float l = lsum[g];
        l += __shfl_xor(l, 16);
        l += __shfl_xor(l, 32);
        const float inv = 1.0f / l;
#pragma unroll
        for (int r = 0; r < 4; ++r) {
            const float invr = __shfl(inv, quad * 4 + r);
            const int q = qw + g * 16 + quad * 4 + r;
            const size_t base = ((size_t)b * Ss + q) * NXx + h * HDd;
#pragma unroll
            for (int f = 0; f < 4; ++f)
                about[base + f * 16 + lrow] = f2bf(O[g][f][r] * invr);
        }
    }
}

// ---------------- launch ----------------
extern "C" void kernel_launch(void* const* d_in, const int* in_sizes, int n_in,
                              void* d_out, int out_size, void* d_ws, size_t ws_size,
                              hipStream_t stream) {
    const float* x        = (const float*)d_in[0];
    const float* query    = (const float*)d_in[1];
    const float* c_attn_w = (const float*)d_in[2];
    const float* c_attn_b = (const float*)d_in[3];
    const float* c_proj_w = (const float*)d_in[4];
    const float* c_proj_b = (const float*)d_in[5];
    float* out = (float*)d_out;

    const size_t nTok = (size_t)Mm * NXx;          // 8388608
    char* ws = (char*)d_ws;
    unsigned short* xb    = (unsigned short*)ws;                 ws += nTok * 2;
    unsigned short* qb    = (unsigned short*)ws;                 ws += nTok * 2;
    unsigned short* Wt    = (unsigned short*)ws;                 ws += (size_t)3 * NXx * NXx * 2;  // [3072][1024]
    unsigned short* Pt    = (unsigned short*)ws;                 ws += (size_t)NXx * NXx * 2;      // [1024][1024]
    unsigned short* Qh    = (unsigned short*)ws;                 ws += nTok * 2;
    unsigned short* Kh    = (unsigned short*)ws;                 ws += nTok * 2;
    unsigned short* Vt    = (unsigned short*)ws;                 ws += nTok * 2;
    unsigned short* about = (unsigned short*)ws;                 ws += nTok * 2;
    if ((size_t)(ws - (char*)d_ws) > ws_size) return;

    // merged prep: casts + transposes
    prep<<<20480, 256, 0, stream>>>(x, query, c_attn_w, c_proj_w, xb, qb, Wt, Pt);

    // QKV: M=8192, N=3072, K=1024 — 256x128 tiles, BK=32, r4-verified config
    gemm256<<<768, 512, 0, stream>>>(xb, qb, Wt, c_attn_b, 0,
                                     Qh, Kh, Vt, nullptr);

    // causal flash attention (pipelined double-buffer staging)
    flash_attn<<<512, 256, 0, stream>>>(Qh, Kh, Vt, about);

    // output projection: M=8192, N=1024, K=1024 — same structure, 256 blocks = 1 round
    gemm256<<<256, 512, 0, stream>>>(about, nullptr, Pt, c_proj_b, 1,
                                     nullptr, nullptr, nullptr, out);
}

// Round 7
// 258.143 us; speedup vs baseline: 2.7911x; 1.0116x over previous
//
#include <hip/hip_runtime.h>
#include <cstdint>
#include <cstddef>

// Problem constants (fixed by reference)
#define Bb   8
#define Ss   1024
#define NXx  1024
#define Hh   16
#define HDd  64
#define Mm   (Bb*Ss)      // 8192 rows

typedef __bf16 bf16x8 __attribute__((ext_vector_type(8)));
typedef float  f32x4  __attribute__((ext_vector_type(4)));

// cheap near-RNE fp32->bf16 (2 VALU ops); accuracy headroom is ~4x vs threshold
__device__ __forceinline__ unsigned short f2bf(float f) {
    union { float f; unsigned int u; } v; v.f = f;
    return (unsigned short)((v.u + 0x8000u) >> 16);
}
__device__ __forceinline__ unsigned int f2bf_hi(float f) {   // bf16 in high half
    union { float f; unsigned int u; } v; v.f = f;
    return (v.u + 0x8000u) & 0xffff0000u;
}

// async global->LDS, 16B per lane; LDS dest = wave-uniform base + lane*16
__device__ __forceinline__ void load_lds16(const unsigned short* g, unsigned short* lds_base) {
    __builtin_amdgcn_global_load_lds(
        (const __attribute__((address_space(1))) void*)g,
        (__attribute__((address_space(3))) void*)lds_base, 16, 0, 0);
}

// ---------------- merged prep: casts + weight transposes in one dispatch ----------------
__global__ __launch_bounds__(256) void prep(
    const float* __restrict__ x, const float* __restrict__ query,
    const float* __restrict__ caw, const float* __restrict__ cpw,
    unsigned short* __restrict__ xb, unsigned short* __restrict__ qb,
    unsigned short* __restrict__ Wt, unsigned short* __restrict__ Pt)
{
    __shared__ float tile[32][33];
    const int bid = blockIdx.x;
    const int tid = threadIdx.x;

    if (bid < 16384) {
        const float* in = (bid < 8192) ? x : query;
        unsigned short* out = (bid < 8192) ? xb : qb;
        const int i = ((bid & 8191) * 256 + tid) * 4;
        const float4 v = *(const float4*)(in + i);
        unsigned long long p = (unsigned long long)f2bf(v.x)
            | ((unsigned long long)f2bf(v.y) << 16)
            | ((unsigned long long)f2bf(v.z) << 32)
            | ((unsigned long long)f2bf(v.w) << 48);
        *(unsigned long long*)(out + i) = p;
        return;
    }

    const float* in;
    unsigned short* out;
    int C, t;
    if (bid < 16384 + 3072) { in = caw; out = Wt; C = 3072; t = bid - 16384; }
    else                    { in = cpw; out = Pt; C = 1024; t = bid - 19456; }
    const int ntx = C >> 5;
    const int c0 = (t % ntx) * 32, r0 = (t / ntx) * 32;
    const int tx = tid & 31, ty = tid >> 5;
    for (int i = ty; i < 32; i += 8)
        tile[i][tx] = in[(size_t)(r0 + i) * C + c0 + tx];
    __syncthreads();
    for (int i = ty; i < 32; i += 8)
        out[(size_t)(c0 + i) * 1024 + r0 + tx] = f2bf(tile[tx][i]);
}

// ---------------- 128x128-tile bf16 MFMA GEMM, BK=64 (proj, mode 1 — r4-verified) ----------------
__global__ __launch_bounds__(256) void gemm128(
    const unsigned short* __restrict__ Ax,
    const unsigned short* __restrict__ Aq,
    const unsigned short* __restrict__ Bt,
    const float* __restrict__ bias,
    int K, int mode,
    unsigned short* __restrict__ out_q,
    unsigned short* __restrict__ out_k,
    unsigned short* __restrict__ out_v,
    float* __restrict__ out_f)
{
    __shared__ unsigned short smem[16384];    // 32 KB staging; reused for epilogue bounce
    unsigned short (*As)[64] = (unsigned short (*)[64])(smem);
    unsigned short (*Bs)[64] = (unsigned short (*)[64])(smem + 8192);

    const int tid  = threadIdx.x;
    const int w    = tid >> 6;
    const int lane = tid & 63;

    // XCD-aware 2-D supertile swizzle: XCD (n&7) -> 16y x (nx/2)x block
    const int nx   = (mode == 0) ? 24 : 8;
    const int nxh  = nx >> 1;
    const int n    = blockIdx.x;
    const int xcd  = n & 7;
    const int sgrp = n >> 3;
    const int m0   = ((xcd >> 1) * 16 + sgrp / nxh) * 128;
    const int n0   = ((xcd & 1) * nxh + sgrp % nxh) * 128;
    const int region = n0 >> 10;
    const unsigned short* A = (mode == 0 && region == 0) ? Aq : Ax;

    const int wm   = (w >> 1) * 64;
    const int wn   = (w & 1) * 64;
    const int lrow = lane & 15;
    const int quad = lane >> 4;

    f32x4 acc[4][4] = {};

    // staging: wave w covers rows [w*32, w*32+32) in 4 calls of 8 rows each.
    const int rr   = lane >> 3;
    const int scol = (((lane & 7) ^ (lane >> 3)) << 3);
    const unsigned short* Ag = A  + (size_t)(m0 + w * 32 + rr) * K + scol;
    const unsigned short* Bg = Bt + (size_t)(n0 + w * 32 + rr) * K + scol;
    unsigned short* ldsA = smem + (w * 32) * 64;
    unsigned short* ldsB = smem + 8192 + (w * 32) * 64;

    const int swz = lrow & 7;                 // fragment-read swizzle

    for (int k0 = 0; k0 < K; k0 += 64) {
        __syncthreads();
#pragma unroll
        for (int c = 0; c < 4; ++c) {
            load_lds16(Ag + (size_t)(c * 8) * K + k0, ldsA + c * 512);
            load_lds16(Bg + (size_t)(c * 8) * K + k0, ldsB + c * 512);
        }
        __syncthreads();
#pragma unroll
        for (int kk = 0; kk < 2; ++kk) {
            bf16x8 af[4], bfr[4];
            const int pc = (((kk * 4 + quad) ^ swz) << 3);
#pragma unroll
            for (int i = 0; i < 4; ++i) {
                af[i]  = *(const bf16x8*)&As[wm + i * 16 + lrow][pc];
                bfr[i] = *(const bf16x8*)&Bs[wn + i * 16 + lrow][pc];
            }
#pragma unroll
            for (int i = 0; i < 4; ++i)
#pragma unroll
                for (int j = 0; j < 4; ++j)
                    acc[i][j] = __builtin_amdgcn_mfma_f32_16x16x32_bf16(af[i], bfr[j], acc[i][j], 0, 0, 0);
        }
    }

    __syncthreads();   // all waves done reading As/Bs; safe to reuse smem

    if (mode == 1) {
#pragma unroll
        for (int i = 0; i < 4; ++i)
#pragma unroll
            for (int j = 0; j < 4; ++j) {
                const int ncol = n0 + wn + j * 16 + lrow;
                const float bv = bias[ncol];
#pragma unroll
                for (int r = 0; r < 4; ++r) {
                    const int mrow = m0 + wm + i * 16 + quad * 4 + r;
                    out_f[(size_t)mrow * NXx + ncol] = acc[i][j][r] + bv;
                }
            }
        return;
    }

    unsigned short* ep = smem + w * 2048;     // per-wave 4 KB bounce region

    if (region != 2) {
        unsigned short* outp = (region == 0) ? out_q : out_k;
#pragma unroll
        for (int j = 0; j < 4; ++j) {
            const float bv = bias[n0 + wn + j * 16 + lrow];
#pragma unroll
            for (int i = 0; i < 4; ++i)
#pragma unroll
                for (int r = 0; r < 4; ++r)
                    ep[(i * 16 + quad * 4 + r) * 24 + lrow] = f2bf(acc[i][j][r] + bv);
#pragma unroll
            for (int t = 0; t < 2; ++t) {
                const int c    = t * 64 + lane;
                const int row  = c >> 1, ch = (c & 1) * 8;
                const int mrow = m0 + wm + row;
                const int cc   = (n0 + wn + j * 16 + ch) & (NXx - 1);
                const int hh   = cc >> 6, dd = cc & 63;
                const int bh   = (mrow >> 10) * Hh + hh;
                const int ss   = mrow & (Ss - 1);
                *(uint4*)&outp[((size_t)bh * Ss + ss) * HDd + dd] =
                    *(const uint4*)&ep[row * 24 + ch];
            }
        }
    } else {
#pragma unroll
        for (int j = 0; j < 4; ++j) {
            const float bv = bias[n0 + wn + j * 16 + lrow];
#pragma unroll
            for (int i = 0; i < 4; ++i)
#pragma unroll
                for (int r = 0; r < 4; ++r)
                    ep[lrow * 72 + i * 16 + quad * 4 + r] = f2bf(acc[i][j][r] + bv);
#pragma unroll
            for (int t = 0; t < 2; ++t) {
                const int c    = t * 64 + lane;
                const int col  = c >> 3, rc = (c & 7) * 8;
                const int cc   = (n0 + wn + j * 16 + col) & (NXx - 1);
                const int hh   = cc >> 6, dd = cc & 63;
                const int mrow = m0 + wm + rc;
                const int bh   = (mrow >> 10) * Hh + hh;
                const int ss   = mrow & (Ss - 1);
                *(uint4*)&out_v[((size_t)bh * HDd + dd) * Ss + ss] =
                    *(const uint4*)&ep[col * 72 + rc];
            }
        }
    }
}

// ---------------- 256x128-tile QKV GEMM: BK=32, 72KB triple-buffer, 2 blocks/CU ----------------
// r4-verified config (64.6us, VGPR 60, no spill). Do NOT raise min-waves past 4
// (r5: (512,6) capped VGPR at 85 -> acc spilled to scratch, FETCH 51->898MB, 531us).
__global__ __launch_bounds__(512, 4) void gemm256(
    const unsigned short* __restrict__ Ax,
    const unsigned short* __restrict__ Aq,
    const unsigned short* __restrict__ Bt,
    const float* __restrict__ bias,
    unsigned short* __restrict__ out_q,
    unsigned short* __restrict__ out_k,
    unsigned short* __restrict__ out_v)
{
    __shared__ unsigned short lds[36864];   // 72 KB: 3 x (A[256][32]=16KB | B[128][32]=8KB)

    const int tid  = threadIdx.x;
    const int w    = tid >> 6;
    const int lane = tid & 63;
    const int wm   = (w >> 1) * 64;         // 4 M-waves x 64 rows
    const int wn   = (w & 1) * 64;          // 2 N-waves x 64 cols
    const int lrow = lane & 15;
    const int quad = lane >> 4;
    const int ph   = (quad ^ (lrow & 3) ^ (lrow >> 2)) & 3;   // frag-read phys chunk

    // XCD swizzle, ni-fast within XCD: A panel reused by 12 blocks via L2
    const int n    = blockIdx.x;
    const int xcd  = n & 7;
    const int sg   = n >> 3;                     // 0..95
    const int mi   = (xcd >> 1) * 8 + sg / 12;   // 0..31
    const int ni   = (xcd & 1) * 12 + sg % 12;   // 0..23
    const int m0   = mi << 8;
    const int n0   = ni << 7;
    const int region = n0 >> 10;            // 0=Q 1=K 2=V (block-uniform, BN=128)
    const unsigned short* A = (region == 0) ? Aq : Ax;

    // staging: one load_lds16 = 16 rows x 32 cols (1KB). lane l -> row l>>2, phys l&3;
    // source logical chunk = (l&3) ^ ((l>>2)&3) ^ ((l>>4)&3)
    const int srow = lane >> 2;                  // 0..15
    const int scol = (((lane & 3) ^ (srow & 3) ^ ((srow >> 2) & 3)) << 3);
    const unsigned short* pA0 = A  + (size_t)(m0 + w * 32 + srow) * 1024 + scol;
    const unsigned short* pA1 = A  + (size_t)(m0 + w * 32 + 16 + srow) * 1024 + scol;
    const unsigned short* pB0 = Bt + (size_t)(n0 + w * 16 + srow) * 1024 + scol;

    f32x4 acc[4][4] = {};

    // prologue: stage tiles 0,1 into bufs 0,1 (6 loads in flight)
#pragma unroll
    for (int p = 0; p < 2; ++p) {
        const int bb = p * 12288;
        load_lds16(pA0, lds + bb + w * 1024);
        load_lds16(pA1, lds + bb + w * 1024 + 512);
        load_lds16(pB0, lds + bb + 8192 + w * 512);
        pA0 += 32; pA1 += 32; pB0 += 32;
    }

    int cbuf = 0;   // buffer holding tile t
    int sbuf = 2;   // buffer to stage tile t+2 into
#pragma unroll 1
    for (int t = 0; t < 32; ++t) {
        __builtin_amdgcn_s_barrier();       // barA: all reads(t-1) retired -> sbuf free
        asm volatile("" ::: "memory");
        if (t <= 29) {                      // stage tile t+2
            const int bb = sbuf * 12288;
            load_lds16(pA0, lds + bb + w * 1024);
            load_lds16(pA1, lds + bb + w * 1024 + 512);
            load_lds16(pB0, lds + bb + 8192 + w * 512);
            pA0 += 32; pA1 += 32; pB0 += 32;
            asm volatile("s_waitcnt vmcnt(6)" ::: "memory");   // retire tile t's 3
        } else if (t == 30) {
            asm volatile("s_waitcnt vmcnt(3)" ::: "memory");
        } else {
            asm volatile("s_waitcnt vmcnt(0)" ::: "memory");
        }
        __builtin_amdgcn_s_barrier();       // barB: everyone's tile-t staging retired
        asm volatile("" ::: "memory");

        const int rA = cbuf * 12288 + (wm + lrow) * 32 + ph * 8;
        const int rB = cbuf * 12288 + 8192 + (wn + lrow) * 32 + ph * 8;
        bf16x8 af[4], bq[4];
#pragma unroll
        for (int i = 0; i < 4; ++i) af[i] = *(const bf16x8*)&lds[rA + i * 512];
#pragma unroll
        for (int j = 0; j < 4; ++j) bq[j] = *(const bf16x8*)&lds[rB + j * 512];
        // no barrier here: compiler's own-wave lgkmcnt gates each MFMA; waves skew
        __builtin_amdgcn_s_setprio(1);
#pragma unroll
        for (int i = 0; i < 4; ++i)
#pragma unroll
            for (int j = 0; j < 4; ++j)
                acc[i][j] = __builtin_amdgcn_mfma_f32_16x16x32_bf16(af[i], bq[j], acc[i][j], 0, 0, 0);
        __builtin_amdgcn_s_setprio(0);

        cbuf = (cbuf == 2) ? 0 : cbuf + 1;
        sbuf = (sbuf == 2) ? 0 : sbuf + 1;
    }

    __syncthreads();   // full drain; safe to reuse LDS for epilogue bounce

    unsigned short* ep = lds + w * 2048;     // per-wave 4 KB bounce region

    if (region != 2) {
        unsigned short* outp = (region == 0) ? out_q : out_k;
#pragma unroll
        for (int j = 0; j < 4; ++j) {
            const float bv = bias[n0 + wn + j * 16 + lrow];
#pragma unroll
            for (int i = 0; i < 4; ++i)
#pragma unroll
                for (int r = 0; r < 4; ++r)
                    ep[(i * 16 + quad * 4 + r) * 24 + lrow] = f2bf(acc[i][j][r] + bv);
            // per-wave region: in-wave LDS ordering, no barrier needed
#pragma unroll
            for (int tt = 0; tt < 2; ++tt) {
                const int c    = tt * 64 + lane;
                const int row  = c >> 1, ch = (c & 1) * 8;
                const int mrow = m0 + wm + row;
                const int cc   = (n0 + wn + j * 16 + ch) & (NXx - 1);
                const int hh   = cc >> 6, dd = cc & 63;
                const int bh   = (mrow >> 10) * Hh + hh;
                const int ss   = mrow & (Ss - 1);
                *(uint4*)&outp[((size_t)bh * Ss + ss) * HDd + dd] =
                    *(const uint4*)&ep[row * 24 + ch];
            }
        }
    } else {
        // V: bounce transposed [col][row] (stride 72) for contiguous-s wide stores
#pragma unroll
        for (int j = 0; j < 4; ++j) {
            const float bv = bias[n0 + wn + j * 16 + lrow];
#pragma unroll
            for (int i = 0; i < 4; ++i)
#pragma unroll
                for (int r = 0; r < 4; ++r)
                    ep[lrow * 72 + i * 16 + quad * 4 + r] = f2bf(acc[i][j][r] + bv);
#pragma unroll
            for (int tt = 0; tt < 2; ++tt) {
                const int c    = tt * 64 + lane;
                const int col  = c >> 3, rc = (c & 7) * 8;
                const int cc   = (n0 + wn + j * 16 + col) & (NXx - 1);
                const int hh   = cc >> 6, dd = cc & 63;
                const int mrow = m0 + wm + rc;
                const int bh   = (mrow >> 10) * Hh + hh;
                const int ss   = mrow & (Ss - 1);
                *(uint4*)&out_v[((size_t)bh * HDd + dd) * Ss + ss] =
                    *(const uint4*)&ep[col * 72 + rc];
            }
        }
    }
}

// ---------------- flash-style causal attention, S^T, 8-wave 256-row supertiles ----------------
// 256 blocks x 512 thr: block = (bh, pair prg); q-supertiles of 256 rows, pairs
// (0,3)/(1,2) -> uniform 20 K-iterations; 8 waves share each 64-key K/V tile.
// Staging drops 295->164 MB vs the 4-wave/128-row version (waves on machine equal:
// 256x8 = 512x4). Triple-buffered depth-2 staging: per iter each wave issues 2
// loads (K rows w*8..+8, V rows d=w*8..+8) for tile it+2; counted vmcnt(4)
// (= 2 tiles x 2 loads in flight) / 2 / 0 at the tail. Q-reload loads at the half
// transition are newer than any staging load being retired -> counted waits only
// over-wait (safe; same argument verified in r5/r6). Masking/skip is wave-level;
// all barrier control (nkt0 = 4*prg+4) is block-uniform.
__global__ __launch_bounds__(512) void flash_attn(
    const unsigned short* __restrict__ Qh,
    const unsigned short* __restrict__ Kh,
    const unsigned short* __restrict__ Vt,
    unsigned short* __restrict__ about)
{
    __shared__ unsigned short Ks[3][64][64];     // phys_chunk = log ^ (row&7)
    __shared__ unsigned short Vs[3][64][64];
    __shared__ unsigned short Pl[8][32][72];     // per-wave P, [q][key], stride 144B

    const int tid  = threadIdx.x;
    const int w    = tid >> 6;                   // 0..7
    const int lane = tid & 63;
    const int bh   = blockIdx.x & 127;
    const int prg  = blockIdx.x >> 7;            // 0 -> (st 0,3), 1 -> (st 1,2)
    const int b    = bh >> 4, h = bh & 15;
    const int lrow = lane & 15;
    const int quad = lane >> 4;

    const unsigned short* Qb = Qh + (size_t)bh * Ss * HDd;
    const unsigned short* Kb = Kh + (size_t)bh * Ss * HDd;
    const unsigned short* Vb = Vt + (size_t)bh * HDd * Ss;

    // staging: 1 call of 8 rows per matrix per wave; source col permuted
    const int sr = lane >> 3;
    const int lc = (((lane & 7) ^ sr) << 3);

    const int swz = lrow & 7;
    const int ca = ((quad ^ swz) << 3);            // k/d 0..31
    const int cb = (((4 + quad) ^ swz) << 3);      // k/d 32..63

    const int nkt0 = 4 * prg + 4;                  // half-A iters; total = 20
    int qw = prg * 256 + w * 32;                   // wave's first q row

    bf16x8 aq[2][2];
#pragma unroll
    for (int g = 0; g < 2; ++g)
#pragma unroll
        for (int c = 0; c < 2; ++c)
            aq[g][c] = *(const bf16x8*)(Qb + (size_t)(qw + g * 16 + lrow) * HDd + c * 32 + quad * 8);

    f32x4 O[2][4] = {};
    float lsum[2] = { 0.f, 0.f };

    // prologue: stage iters 0,1 (k0 = 0,64 — both half-A since nkt0 >= 4) into bufs 0,1
#pragma unroll
    for (int p = 0; p < 2; ++p) {
        load_lds16(Kb + (size_t)(p * 64 + w * 8 + sr) * HDd + lc, &Ks[p][w * 8][0]);
        load_lds16(Vb + (size_t)(w * 8 + sr) * Ss + p * 64 + lc,  &Vs[p][w * 8][0]);
    }

    int cbuf = 0;   // buffer holding iter it
    int sbuf = 2;   // buffer to stage iter it+2 into
#pragma unroll 1
    for (int it = 0; it < 20; ++it) {
        __builtin_amdgcn_s_barrier();   // barA: all reads of sbuf (iter it-1) done
        asm volatile("" ::: "memory");
        if (it <= 17) {
            const int itn = it + 2;
            const int k0n = (itn >= nkt0 ? itn - nkt0 : itn) * 64;
            load_lds16(Kb + (size_t)(k0n + w * 8 + sr) * HDd + lc, &Ks[sbuf][w * 8][0]);
            load_lds16(Vb + (size_t)(w * 8 + sr) * Ss + k0n + lc,  &Vs[sbuf][w * 8][0]);
            asm volatile("s_waitcnt vmcnt(4)" ::: "memory");   // retire iter-it's 2
        } else if (it == 18) {
            asm volatile("s_waitcnt vmcnt(2)" ::: "memory");
        } else {
            asm volatile("s_waitcnt vmcnt(0)" ::: "memory");
        }
        __builtin_amdgcn_s_barrier();   // barB: everyone's iter-it staging retired
        asm volatile("" ::: "memory");

        if (it == nkt0) {
            // finish half A: quad-reduce l, normalize, store (registers + shfl only)
#pragma unroll
            for (int g = 0; g < 2; ++g) {
                float l = lsum[g];
                l += __shfl_xor(l, 16);
                l += __shfl_xor(l, 32);
                const float inv = 1.0f / l;
#pragma unroll
                for (int r = 0; r < 4; ++r) {
                    const float invr = __shfl(inv, quad * 4 + r);
                    const int q = qw + g * 16 + quad * 4 + r;
                    const size_t base = ((size_t)b * Ss + q) * NXx + h * HDd;
#pragma unroll
                    for (int f = 0; f < 4; ++f)
                        about[base + f * 16 + lrow] = f2bf(O[g][f][r] * invr);
                }
            }
            // switch to half B (supertile 3-prg)
            qw = (3 - prg) * 256 + w * 32;
#pragma unroll
            for (int g = 0; g < 2; ++g)
#pragma unroll
                for (int c = 0; c < 2; ++c)
                    aq[g][c] = *(const bf16x8*)(Qb + (size_t)(qw + g * 16 + lrow) * HDd + c * 32 + quad * 8);
#pragma unroll
            for (int g = 0; g < 2; ++g) {
                lsum[g] = 0.f;
#pragma unroll
                for (int f = 0; f < 4; ++f) O[g][f] = (f32x4){0.f, 0.f, 0.f, 0.f};
            }
        }

        const int k0 = (it >= nkt0 ? it - nkt0 : it) * 64;
        if (k0 <= qw + 31) {                   // else fully masked (wave-uniform)
            // S^T = K·Q^T: D[key = j*16+quad*4+r][q = g*16+lrow]
            f32x4 st[2][4] = {};
#pragma unroll
            for (int j = 0; j < 4; ++j) {
                const bf16x8 kf0 = *(const bf16x8*)&Ks[cbuf][j * 16 + lrow][ca];
                const bf16x8 kf1 = *(const bf16x8*)&Ks[cbuf][j * 16 + lrow][cb];
                st[0][j] = __builtin_amdgcn_mfma_f32_16x16x32_bf16(kf0, aq[0][0], st[0][j], 0, 0, 0);
                st[0][j] = __builtin_amdgcn_mfma_f32_16x16x32_bf16(kf1, aq[0][1], st[0][j], 0, 0, 0);
                st[1][j] = __builtin_amdgcn_mfma_f32_16x16x32_bf16(kf0, aq[1][0], st[1][j], 0, 0, 0);
                st[1][j] = __builtin_amdgcn_mfma_f32_16x16x32_bf16(kf1, aq[1][1], st[1][j], 0, 0, 0);
            }

            const bool needMask = (k0 + 63 > qw);  // wave-uniform
#pragma unroll
            for (int g = 0; g < 2; ++g) {
                const int qg = qw + g * 16 + lrow;  // this lane's q row
#pragma unroll
                for (int j = 0; j < 4; ++j) {
                    const int kbase = k0 + j * 16 + quad * 4;
                    float e0 = __expf(st[g][j][0] * 0.125f);
                    float e1 = __expf(st[g][j][1] * 0.125f);
                    float e2 = __expf(st[g][j][2] * 0.125f);
                    float e3 = __expf(st[g][j][3] * 0.125f);
                    if (needMask) {
                        if (kbase     > qg) e0 = 0.f;
                        if (kbase + 1 > qg) e1 = 0.f;
                        if (kbase + 2 > qg) e2 = 0.f;
                        if (kbase + 3 > qg) e3 = 0.f;
                    }
                    lsum[g] += (e0 + e1) + (e2 + e3);
                    uint2 pk;
                    pk.x = (unsigned)f2bf(e0) | f2bf_hi(e1);
                    pk.y = (unsigned)f2bf(e2) | f2bf_hi(e3);
                    *(uint2*)&Pl[w][g * 16 + lrow][j * 16 + quad * 4] = pk;
                }
            }
            // Pl[w] is per-wave: in-wave DS ordering suffices, no barrier

            bf16x8 ap[2][2];
#pragma unroll
            for (int g = 0; g < 2; ++g)
#pragma unroll
                for (int c = 0; c < 2; ++c)
                    ap[g][c] = *(const bf16x8*)&Pl[w][g * 16 + lrow][c * 32 + quad * 8];
#pragma unroll
            for (int f = 0; f < 4; ++f) {
                const bf16x8 vf0 = *(const bf16x8*)&Vs[cbuf][f * 16 + lrow][ca];
                const bf16x8 vf1 = *(const bf16x8*)&Vs[cbuf][f * 16 + lrow][cb];
                O[0][f] = __builtin_amdgcn_mfma_f32_16x16x32_bf16(ap[0][0], vf0, O[0][f], 0, 0, 0);
                O[0][f] = __builtin_amdgcn_mfma_f32_16x16x32_bf16(ap[0][1], vf1, O[0][f], 0, 0, 0);
                O[1][f] = __builtin_amdgcn_mfma_f32_16x16x32_bf16(ap[1][0], vf0, O[1][f], 0, 0, 0);
                O[1][f] = __builtin_amdgcn_mfma_f32_16x16x32_bf16(ap[1][1], vf1, O[1][f], 0, 0, 0);
            }
        }

        cbuf = (cbuf == 2) ? 0 : cbuf + 1;
        sbuf = (sbuf == 2) ? 0 : sbuf + 1;
    }

    // final epilogue: half B
#pragma unroll
    for (int g = 0; g < 2; ++g) {
        float l = lsum[g];
        l += __shfl_xor(l, 16);
        l += __shfl_xor(l, 32);
        const float inv = 1.0f / l;
#pragma unroll
        for (int r = 0; r < 4; ++r) {
            const float invr = __shfl(inv, quad * 4 + r);
            const int q = qw + g * 16 + quad * 4 + r;
            const size_t base = ((size_t)b * Ss + q) * NXx + h * HDd;
#pragma unroll
            for (int f = 0; f < 4; ++f)
                about[base + f * 16 + lrow] = f2bf(O[g][f][r] * invr);
        }
    }
}

// ---------------- launch ----------------
extern "C" void kernel_launch(void* const* d_in, const int* in_sizes, int n_in,
                              void* d_out, int out_size, void* d_ws, size_t ws_size,
                              hipStream_t stream) {
    const float* x        = (const float*)d_in[0];
    const float* query    = (const float*)d_in[1];
    const float* c_attn_w = (const float*)d_in[2];
    const float* c_attn_b = (const float*)d_in[3];
    const float* c_proj_w = (const float*)d_in[4];
    const float* c_proj_b = (const float*)d_in[5];
    float* out = (float*)d_out;

    const size_t nTok = (size_t)Mm * NXx;          // 8388608
    char* ws = (char*)d_ws;
    unsigned short* xb    = (unsigned short*)ws;                 ws += nTok * 2;
    unsigned short* qb    = (unsigned short*)ws;                 ws += nTok * 2;
    unsigned short* Wt    = (unsigned short*)ws;                 ws += (size_t)3 * NXx * NXx * 2;  // [3072][1024]
    unsigned short* Pt    = (unsigned short*)ws;                 ws += (size_t)NXx * NXx * 2;      // [1024][1024]
    unsigned short* Qh    = (unsigned short*)ws;                 ws += nTok * 2;
    unsigned short* Kh    = (unsigned short*)ws;                 ws += nTok * 2;
    unsigned short* Vt    = (unsigned short*)ws;                 ws += nTok * 2;
    unsigned short* about = (unsigned short*)ws;                 ws += nTok * 2;
    if ((size_t)(ws - (char*)d_ws) > ws_size) return;

    // merged prep: casts + transposes
    prep<<<20480, 256, 0, stream>>>(x, query, c_attn_w, c_proj_w, xb, qb, Wt, Pt);

    // QKV: M=8192, N=3072, K=1024 — 256x128 tiles, BK=32, r4-verified config
    gemm256<<<768, 512, 0, stream>>>(xb, qb, Wt, c_attn_b, Qh, Kh, Vt);

    // causal flash attention (8-wave 256-row supertile pairs, depth-2 staging)
    flash_attn<<<256, 512, 0, stream>>>(Qh, Kh, Vt, about);

    // output projection: M=8192, N=1024, K=1024 -> fp32 out (gemm128, measured-best)
    gemm128<<<dim3(8 * 64), 256, 0, stream>>>(about, nullptr, Pt, c_proj_b, NXx, 1,
                                              nullptr, nullptr, nullptr, out);
}

// Round 8
// 254.239 us; speedup vs baseline: 2.8339x; 1.0154x over previous
//
#include <hip/hip_runtime.h>
#include <cstdint>
#include <cstddef>

// Problem constants (fixed by reference)
#define Bb   8
#define Ss   1024
#define NXx  1024
#define Hh   16
#define HDd  64
#define Mm   (Bb*Ss)      // 8192 rows

typedef __bf16 bf16x8 __attribute__((ext_vector_type(8)));
typedef float  f32x4  __attribute__((ext_vector_type(4)));

// cheap near-RNE fp32->bf16 (2 VALU ops); accuracy headroom is ~4x vs threshold
__device__ __forceinline__ unsigned short f2bf(float f) {
    union { float f; unsigned int u; } v; v.f = f;
    return (unsigned short)((v.u + 0x8000u) >> 16);
}

// packed fp32x2 -> bf16x2 (RNE), single VOP3 — replaces ~5 bit-ops per pair
__device__ __forceinline__ unsigned cvt_pk_bf16(float lo, float hi) {
    unsigned r;
    asm("v_cvt_pk_bf16_f32 %0, %1, %2" : "=v"(r) : "v"(lo), "v"(hi));
    return r;
}

// async global->LDS, 16B per lane; LDS dest = wave-uniform base + lane*16
__device__ __forceinline__ void load_lds16(const unsigned short* g, unsigned short* lds_base) {
    __builtin_amdgcn_global_load_lds(
        (const __attribute__((address_space(1))) void*)g,
        (__attribute__((address_space(3))) void*)lds_base, 16, 0, 0);
}

// ---------------- merged prep: casts + weight transposes in one dispatch ----------------
__global__ __launch_bounds__(256) void prep(
    const float* __restrict__ x, const float* __restrict__ query,
    const float* __restrict__ caw, const float* __restrict__ cpw,
    unsigned short* __restrict__ xb, unsigned short* __restrict__ qb,
    unsigned short* __restrict__ Wt, unsigned short* __restrict__ Pt)
{
    __shared__ float tile[32][33];
    const int bid = blockIdx.x;
    const int tid = threadIdx.x;

    if (bid < 16384) {
        const float* in = (bid < 8192) ? x : query;
        unsigned short* out = (bid < 8192) ? xb : qb;
        const int i = ((bid & 8191) * 256 + tid) * 4;
        const float4 v = *(const float4*)(in + i);
        unsigned long long p = (unsigned long long)f2bf(v.x)
            | ((unsigned long long)f2bf(v.y) << 16)
            | ((unsigned long long)f2bf(v.z) << 32)
            | ((unsigned long long)f2bf(v.w) << 48);
        *(unsigned long long*)(out + i) = p;
        return;
    }

    const float* in;
    unsigned short* out;
    int C, t;
    if (bid < 16384 + 3072) { in = caw; out = Wt; C = 3072; t = bid - 16384; }
    else                    { in = cpw; out = Pt; C = 1024; t = bid - 19456; }
    const int ntx = C >> 5;
    const int c0 = (t % ntx) * 32, r0 = (t / ntx) * 32;
    const int tx = tid & 31, ty = tid >> 5;
    for (int i = ty; i < 32; i += 8)
        tile[i][tx] = in[(size_t)(r0 + i) * C + c0 + tx];
    __syncthreads();
    for (int i = ty; i < 32; i += 8)
        out[(size_t)(c0 + i) * 1024 + r0 + tx] = f2bf(tile[tx][i]);
}

// ---------------- 128x128-tile bf16 MFMA GEMM, BK=64 (proj, mode 1 — r4-verified) ----------------
__global__ __launch_bounds__(256) void gemm128(
    const unsigned short* __restrict__ Ax,
    const unsigned short* __restrict__ Aq,
    const unsigned short* __restrict__ Bt,
    const float* __restrict__ bias,
    int K, int mode,
    unsigned short* __restrict__ out_q,
    unsigned short* __restrict__ out_k,
    unsigned short* __restrict__ out_v,
    float* __restrict__ out_f)
{
    __shared__ unsigned short smem[16384];    // 32 KB staging; reused for epilogue bounce
    unsigned short (*As)[64] = (unsigned short (*)[64])(smem);
    unsigned short (*Bs)[64] = (unsigned short (*)[64])(smem + 8192);

    const int tid  = threadIdx.x;
    const int w    = tid >> 6;
    const int lane = tid & 63;

    // XCD-aware 2-D supertile swizzle: XCD (n&7) -> 16y x (nx/2)x block
    const int nx   = (mode == 0) ? 24 : 8;
    const int nxh  = nx >> 1;
    const int n    = blockIdx.x;
    const int xcd  = n & 7;
    const int sgrp = n >> 3;
    const int m0   = ((xcd >> 1) * 16 + sgrp / nxh) * 128;
    const int n0   = ((xcd & 1) * nxh + sgrp % nxh) * 128;
    const int region = n0 >> 10;
    const unsigned short* A = (mode == 0 && region == 0) ? Aq : Ax;

    const int wm   = (w >> 1) * 64;
    const int wn   = (w & 1) * 64;
    const int lrow = lane & 15;
    const int quad = lane >> 4;

    f32x4 acc[4][4] = {};

    // staging: wave w covers rows [w*32, w*32+32) in 4 calls of 8 rows each.
    const int rr   = lane >> 3;
    const int scol = (((lane & 7) ^ (lane >> 3)) << 3);
    const unsigned short* Ag = A  + (size_t)(m0 + w * 32 + rr) * K + scol;
    const unsigned short* Bg = Bt + (size_t)(n0 + w * 32 + rr) * K + scol;
    unsigned short* ldsA = smem + (w * 32) * 64;
    unsigned short* ldsB = smem + 8192 + (w * 32) * 64;

    const int swz = lrow & 7;                 // fragment-read swizzle

    for (int k0 = 0; k0 < K; k0 += 64) {
        __syncthreads();
#pragma unroll
        for (int c = 0; c < 4; ++c) {
            load_lds16(Ag + (size_t)(c * 8) * K + k0, ldsA + c * 512);
            load_lds16(Bg + (size_t)(c * 8) * K + k0, ldsB + c * 512);
        }
        __syncthreads();
#pragma unroll
        for (int kk = 0; kk < 2; ++kk) {
            bf16x8 af[4], bfr[4];
            const int pc = (((kk * 4 + quad) ^ swz) << 3);
#pragma unroll
            for (int i = 0; i < 4; ++i) {
                af[i]  = *(const bf16x8*)&As[wm + i * 16 + lrow][pc];
                bfr[i] = *(const bf16x8*)&Bs[wn + i * 16 + lrow][pc];
            }
#pragma unroll
            for (int i = 0; i < 4; ++i)
#pragma unroll
                for (int j = 0; j < 4; ++j)
                    acc[i][j] = __builtin_amdgcn_mfma_f32_16x16x32_bf16(af[i], bfr[j], acc[i][j], 0, 0, 0);
        }
    }

    __syncthreads();   // all waves done reading As/Bs; safe to reuse smem

    if (mode == 1) {
#pragma unroll
        for (int i = 0; i < 4; ++i)
#pragma unroll
            for (int j = 0; j < 4; ++j) {
                const int ncol = n0 + wn + j * 16 + lrow;
                const float bv = bias[ncol];
#pragma unroll
                for (int r = 0; r < 4; ++r) {
                    const int mrow = m0 + wm + i * 16 + quad * 4 + r;
                    out_f[(size_t)mrow * NXx + ncol] = acc[i][j][r] + bv;
                }
            }
        return;
    }

    unsigned short* ep = smem + w * 2048;     // per-wave 4 KB bounce region

    if (region != 2) {
        unsigned short* outp = (region == 0) ? out_q : out_k;
#pragma unroll
        for (int j = 0; j < 4; ++j) {
            const float bv = bias[n0 + wn + j * 16 + lrow];
#pragma unroll
            for (int i = 0; i < 4; ++i)
#pragma unroll
                for (int r = 0; r < 4; ++r)
                    ep[(i * 16 + quad * 4 + r) * 24 + lrow] = f2bf(acc[i][j][r] + bv);
#pragma unroll
            for (int t = 0; t < 2; ++t) {
                const int c    = t * 64 + lane;
                const int row  = c >> 1, ch = (c & 1) * 8;
                const int mrow = m0 + wm + row;
                const int cc   = (n0 + wn + j * 16 + ch) & (NXx - 1);
                const int hh   = cc >> 6, dd = cc & 63;
                const int bh   = (mrow >> 10) * Hh + hh;
                const int ss   = mrow & (Ss - 1);
                *(uint4*)&outp[((size_t)bh * Ss + ss) * HDd + dd] =
                    *(const uint4*)&ep[row * 24 + ch];
            }
        }
    } else {
#pragma unroll
        for (int j = 0; j < 4; ++j) {
            const float bv = bias[n0 + wn + j * 16 + lrow];
#pragma unroll
            for (int i = 0; i < 4; ++i)
#pragma unroll
                for (int r = 0; r < 4; ++r)
                    ep[lrow * 72 + i * 16 + quad * 4 + r] = f2bf(acc[i][j][r] + bv);
#pragma unroll
            for (int t = 0; t < 2; ++t) {
                const int c    = t * 64 + lane;
                const int col  = c >> 3, rc = (c & 7) * 8;
                const int cc   = (n0 + wn + j * 16 + col) & (NXx - 1);
                const int hh   = cc >> 6, dd = cc & 63;
                const int mrow = m0 + wm + rc;
                const int bh   = (mrow >> 10) * Hh + hh;
                const int ss   = mrow & (Ss - 1);
                *(uint4*)&out_v[((size_t)bh * HDd + dd) * Ss + ss] =
                    *(const uint4*)&ep[col * 72 + rc];
            }
        }
    }
}

// ---------------- 256x128-tile QKV GEMM: BK=32, 72KB triple-buffer, 2 blocks/CU ----------------
// r4-verified config (64.6us, VGPR 60, no spill). Do NOT raise min-waves past 4
// (r5: (512,6) capped VGPR at 85 -> acc spilled to scratch, FETCH 51->898MB, 531us).
// NEW r8: Q-region epilogue stores (acc+bias)*0.125 — folds softmax 1/sqrt(d) into
// Qh so flash_attn's inner loop drops its per-entry mul. Qh feeds ONLY flash_attn.
__global__ __launch_bounds__(512, 4) void gemm256(
    const unsigned short* __restrict__ Ax,
    const unsigned short* __restrict__ Aq,
    const unsigned short* __restrict__ Bt,
    const float* __restrict__ bias,
    unsigned short* __restrict__ out_q,
    unsigned short* __restrict__ out_k,
    unsigned short* __restrict__ out_v)
{
    __shared__ unsigned short lds[36864];   // 72 KB: 3 x (A[256][32]=16KB | B[128][32]=8KB)

    const int tid  = threadIdx.x;
    const int w    = tid >> 6;
    const int lane = tid & 63;
    const int wm   = (w >> 1) * 64;         // 4 M-waves x 64 rows
    const int wn   = (w & 1) * 64;          // 2 N-waves x 64 cols
    const int lrow = lane & 15;
    const int quad = lane >> 4;
    const int ph   = (quad ^ (lrow & 3) ^ (lrow >> 2)) & 3;   // frag-read phys chunk

    // XCD swizzle, ni-fast within XCD: A panel reused by 12 blocks via L2
    const int n    = blockIdx.x;
    const int xcd  = n & 7;
    const int sg   = n >> 3;                     // 0..95
    const int mi   = (xcd >> 1) * 8 + sg / 12;   // 0..31
    const int ni   = (xcd & 1) * 12 + sg % 12;   // 0..23
    const int m0   = mi << 8;
    const int n0   = ni << 7;
    const int region = n0 >> 10;            // 0=Q 1=K 2=V (block-uniform, BN=128)
    const unsigned short* A = (region == 0) ? Aq : Ax;

    // staging: one load_lds16 = 16 rows x 32 cols (1KB). lane l -> row l>>2, phys l&3;
    // source logical chunk = (l&3) ^ ((l>>2)&3) ^ ((l>>4)&3)
    const int srow = lane >> 2;                  // 0..15
    const int scol = (((lane & 3) ^ (srow & 3) ^ ((srow >> 2) & 3)) << 3);
    const unsigned short* pA0 = A  + (size_t)(m0 + w * 32 + srow) * 1024 + scol;
    const unsigned short* pA1 = A  + (size_t)(m0 + w * 32 + 16 + srow) * 1024 + scol;
    const unsigned short* pB0 = Bt + (size_t)(n0 + w * 16 + srow) * 1024 + scol;

    f32x4 acc[4][4] = {};

    // prologue: stage tiles 0,1 into bufs 0,1 (6 loads in flight)
#pragma unroll
    for (int p = 0; p < 2; ++p) {
        const int bb = p * 12288;
        load_lds16(pA0, lds + bb + w * 1024);
        load_lds16(pA1, lds + bb + w * 1024 + 512);
        load_lds16(pB0, lds + bb + 8192 + w * 512);
        pA0 += 32; pA1 += 32; pB0 += 32;
    }

    int cbuf = 0;   // buffer holding tile t
    int sbuf = 2;   // buffer to stage tile t+2 into
#pragma unroll 1
    for (int t = 0; t < 32; ++t) {
        __builtin_amdgcn_s_barrier();       // barA: all reads(t-1) retired -> sbuf free
        asm volatile("" ::: "memory");
        if (t <= 29) {                      // stage tile t+2
            const int bb = sbuf * 12288;
            load_lds16(pA0, lds + bb + w * 1024);
            load_lds16(pA1, lds + bb + w * 1024 + 512);
            load_lds16(pB0, lds + bb + 8192 + w * 512);
            pA0 += 32; pA1 += 32; pB0 += 32;
            asm volatile("s_waitcnt vmcnt(6)" ::: "memory");   // retire tile t's 3
        } else if (t == 30) {
            asm volatile("s_waitcnt vmcnt(3)" ::: "memory");
        } else {
            asm volatile("s_waitcnt vmcnt(0)" ::: "memory");
        }
        __builtin_amdgcn_s_barrier();       // barB: everyone's tile-t staging retired
        asm volatile("" ::: "memory");

        const int rA = cbuf * 12288 + (wm + lrow) * 32 + ph * 8;
        const int rB = cbuf * 12288 + 8192 + (wn + lrow) * 32 + ph * 8;
        bf16x8 af[4], bq[4];
#pragma unroll
        for (int i = 0; i < 4; ++i) af[i] = *(const bf16x8*)&lds[rA + i * 512];
#pragma unroll
        for (int j = 0; j < 4; ++j) bq[j] = *(const bf16x8*)&lds[rB + j * 512];
        // no barrier here: compiler's own-wave lgkmcnt gates each MFMA; waves skew
        __builtin_amdgcn_s_setprio(1);
#pragma unroll
        for (int i = 0; i < 4; ++i)
#pragma unroll
            for (int j = 0; j < 4; ++j)
                acc[i][j] = __builtin_amdgcn_mfma_f32_16x16x32_bf16(af[i], bq[j], acc[i][j], 0, 0, 0);
        __builtin_amdgcn_s_setprio(0);

        cbuf = (cbuf == 2) ? 0 : cbuf + 1;
        sbuf = (sbuf == 2) ? 0 : sbuf + 1;
    }

    __syncthreads();   // full drain; safe to reuse LDS for epilogue bounce

    unsigned short* ep = lds + w * 2048;     // per-wave 4 KB bounce region

    if (region != 2) {
        unsigned short* outp = (region == 0) ? out_q : out_k;
        const float sc = (region == 0) ? 0.125f : 1.0f;   // fold 1/sqrt(64) into Q
#pragma unroll
        for (int j = 0; j < 4; ++j) {
            const float bv = bias[n0 + wn + j * 16 + lrow];
#pragma unroll
            for (int i = 0; i < 4; ++i)
#pragma unroll
                for (int r = 0; r < 4; ++r)
                    ep[(i * 16 + quad * 4 + r) * 24 + lrow] = f2bf((acc[i][j][r] + bv) * sc);
            // per-wave region: in-wave LDS ordering, no barrier needed
#pragma unroll
            for (int tt = 0; tt < 2; ++tt) {
                const int c    = tt * 64 + lane;
                const int row  = c >> 1, ch = (c & 1) * 8;
                const int mrow = m0 + wm + row;
                const int cc   = (n0 + wn + j * 16 + ch) & (NXx - 1);
                const int hh   = cc >> 6, dd = cc & 63;
                const int bh   = (mrow >> 10) * Hh + hh;
                const int ss   = mrow & (Ss - 1);
                *(uint4*)&outp[((size_t)bh * Ss + ss) * HDd + dd] =
                    *(const uint4*)&ep[row * 24 + ch];
            }
        }
    } else {
        // V: bounce transposed [col][row] (stride 72) for contiguous-s wide stores
#pragma unroll
        for (int j = 0; j < 4; ++j) {
            const float bv = bias[n0 + wn + j * 16 + lrow];
#pragma unroll
            for (int i = 0; i < 4; ++i)
#pragma unroll
                for (int r = 0; r < 4; ++r)
                    ep[lrow * 72 + i * 16 + quad * 4 + r] = f2bf(acc[i][j][r] + bv);
#pragma unroll
            for (int tt = 0; tt < 2; ++tt) {
                const int c    = tt * 64 + lane;
                const int col  = c >> 3, rc = (c & 7) * 8;
                const int cc   = (n0 + wn + j * 16 + col) & (NXx - 1);
                const int hh   = cc >> 6, dd = cc & 63;
                const int mrow = m0 + wm + rc;
                const int bh   = (mrow >> 10) * Hh + hh;
                const int ss   = mrow & (Ss - 1);
                *(uint4*)&out_v[((size_t)bh * HDd + dd) * Ss + ss] =
                    *(const uint4*)&ep[col * 72 + rc];
            }
        }
    }
}

// ---------------- flash-style causal attention, S^T, 8-wave 256-row supertiles ----------------
// r7 structure (measured: staging cut was ~neutral -> interior is VALU-bound).
// r8 VALU diet: (1) Qh pre-scaled by 0.125 in QKV epilogue -> __expf(st) directly,
// no per-entry mul; (2) P packing via v_cvt_pk_bf16_f32 (1 op/pair vs ~5).
// Inner loop/lane/iter: ~208 -> ~112 VALU instrs.
__global__ __launch_bounds__(512) void flash_attn(
    const unsigned short* __restrict__ Qh,
    const unsigned short* __restrict__ Kh,
    const unsigned short* __restrict__ Vt,
    unsigned short* __restrict__ about)
{
    __shared__ unsigned short Ks[3][64][64];     // phys_chunk = log ^ (row&7)
    __shared__ unsigned short Vs[3][64][64];
    __shared__ unsigned short Pl[8][32][72];     // per-wave P, [q][key], stride 144B

    const int tid  = threadIdx.x;
    const int w    = tid >> 6;                   // 0..7
    const int lane = tid & 63;
    const int bh   = blockIdx.x & 127;
    const int prg  = blockIdx.x >> 7;            // 0 -> (st 0,3), 1 -> (st 1,2)
    const int b    = bh >> 4, h = bh & 15;
    const int lrow = lane & 15;
    const int quad = lane >> 4;

    const unsigned short* Qb = Qh + (size_t)bh * Ss * HDd;
    const unsigned short* Kb = Kh + (size_t)bh * Ss * HDd;
    const unsigned short* Vb = Vt + (size_t)bh * HDd * Ss;

    // staging: 1 call of 8 rows per matrix per wave; source col permuted
    const int sr = lane >> 3;
    const int lc = (((lane & 7) ^ sr) << 3);

    const int swz = lrow & 7;
    const int ca = ((quad ^ swz) << 3);            // k/d 0..31
    const int cb = (((4 + quad) ^ swz) << 3);      // k/d 32..63

    const int nkt0 = 4 * prg + 4;                  // half-A iters; total = 20
    int qw = prg * 256 + w * 32;                   // wave's first q row

    bf16x8 aq[2][2];
#pragma unroll
    for (int g = 0; g < 2; ++g)
#pragma unroll
        for (int c = 0; c < 2; ++c)
            aq[g][c] = *(const bf16x8*)(Qb + (size_t)(qw + g * 16 + lrow) * HDd + c * 32 + quad * 8);

    f32x4 O[2][4] = {};
    float lsum[2] = { 0.f, 0.f };

    // prologue: stage iters 0,1 (k0 = 0,64 — both half-A since nkt0 >= 4) into bufs 0,1
#pragma unroll
    for (int p = 0; p < 2; ++p) {
        load_lds16(Kb + (size_t)(p * 64 + w * 8 + sr) * HDd + lc, &Ks[p][w * 8][0]);
        load_lds16(Vb + (size_t)(w * 8 + sr) * Ss + p * 64 + lc,  &Vs[p][w * 8][0]);
    }

    int cbuf = 0;   // buffer holding iter it
    int sbuf = 2;   // buffer to stage iter it+2 into
#pragma unroll 1
    for (int it = 0; it < 20; ++it) {
        __builtin_amdgcn_s_barrier();   // barA: all reads of sbuf (iter it-1) done
        asm volatile("" ::: "memory");
        if (it <= 17) {
            const int itn = it + 2;
            const int k0n = (itn >= nkt0 ? itn - nkt0 : itn) * 64;
            load_lds16(Kb + (size_t)(k0n + w * 8 + sr) * HDd + lc, &Ks[sbuf][w * 8][0]);
            load_lds16(Vb + (size_t)(w * 8 + sr) * Ss + k0n + lc,  &Vs[sbuf][w * 8][0]);
            asm volatile("s_waitcnt vmcnt(4)" ::: "memory");   // retire iter-it's 2
        } else if (it == 18) {
            asm volatile("s_waitcnt vmcnt(2)" ::: "memory");
        } else {
            asm volatile("s_waitcnt vmcnt(0)" ::: "memory");
        }
        __builtin_amdgcn_s_barrier();   // barB: everyone's iter-it staging retired
        asm volatile("" ::: "memory");

        if (it == nkt0) {
            // finish half A: quad-reduce l, normalize, store (registers + shfl only)
#pragma unroll
            for (int g = 0; g < 2; ++g) {
                float l = lsum[g];
                l += __shfl_xor(l, 16);
                l += __shfl_xor(l, 32);
                const float inv = 1.0f / l;
#pragma unroll
                for (int r = 0; r < 4; ++r) {
                    const float invr = __shfl(inv, quad * 4 + r);
                    const int q = qw + g * 16 + quad * 4 + r;
                    const size_t base = ((size_t)b * Ss + q) * NXx + h * HDd;
#pragma unroll
                    for (int f = 0; f < 4; ++f)
                        about[base + f * 16 + lrow] = f2bf(O[g][f][r] * invr);
                }
            }
            // switch to half B (supertile 3-prg)
            qw = (3 - prg) * 256 + w * 32;
#pragma unroll
            for (int g = 0; g < 2; ++g)
#pragma unroll
                for (int c = 0; c < 2; ++c)
                    aq[g][c] = *(const bf16x8*)(Qb + (size_t)(qw + g * 16 + lrow) * HDd + c * 32 + quad * 8);
#pragma unroll
            for (int g = 0; g < 2; ++g) {
                lsum[g] = 0.f;
#pragma unroll
                for (int f = 0; f < 4; ++f) O[g][f] = (f32x4){0.f, 0.f, 0.f, 0.f};
            }
        }

        const int k0 = (it >= nkt0 ? it - nkt0 : it) * 64;
        if (k0 <= qw + 31) {                   // else fully masked (wave-uniform)
            // S^T = K·Q^T: D[key = j*16+quad*4+r][q = g*16+lrow]
            f32x4 st[2][4] = {};
#pragma unroll
            for (int j = 0; j < 4; ++j) {
                const bf16x8 kf0 = *(const bf16x8*)&Ks[cbuf][j * 16 + lrow][ca];
                const bf16x8 kf1 = *(const bf16x8*)&Ks[cbuf][j * 16 + lrow][cb];
                st[0][j] = __builtin_amdgcn_mfma_f32_16x16x32_bf16(kf0, aq[0][0], st[0][j], 0, 0, 0);
                st[0][j] = __builtin_amdgcn_mfma_f32_16x16x32_bf16(kf1, aq[0][1], st[0][j], 0, 0, 0);
                st[1][j] = __builtin_amdgcn_mfma_f32_16x16x32_bf16(kf0, aq[1][0], st[1][j], 0, 0, 0);
                st[1][j] = __builtin_amdgcn_mfma_f32_16x16x32_bf16(kf1, aq[1][1], st[1][j], 0, 0, 0);
            }

            const bool needMask = (k0 + 63 > qw);  // wave-uniform
#pragma unroll
            for (int g = 0; g < 2; ++g) {
                const int qg = qw + g * 16 + lrow;  // this lane's q row
#pragma unroll
                for (int j = 0; j < 4; ++j) {
                    const int kbase = k0 + j * 16 + quad * 4;
                    float e0 = __expf(st[g][j][0]);   // Qh pre-scaled by 0.125
                    float e1 = __expf(st[g][j][1]);
                    float e2 = __expf(st[g][j][2]);
                    float e3 = __expf(st[g][j][3]);
                    if (needMask) {
                        if (kbase     > qg) e0 = 0.f;
                        if (kbase + 1 > qg) e1 = 0.f;
                        if (kbase + 2 > qg) e2 = 0.f;
                        if (kbase + 3 > qg) e3 = 0.f;
                    }
                    lsum[g] += (e0 + e1) + (e2 + e3);
                    uint2 pk;
                    pk.x = cvt_pk_bf16(e0, e1);       // lo=e0, hi=e1
                    pk.y = cvt_pk_bf16(e2, e3);
                    *(uint2*)&Pl[w][g * 16 + lrow][j * 16 + quad * 4] = pk;
                }
            }
            // Pl[w] is per-wave: in-wave DS ordering suffices, no barrier

            bf16x8 ap[2][2];
#pragma unroll
            for (int g = 0; g < 2; ++g)
#pragma unroll
                for (int c = 0; c < 2; ++c)
                    ap[g][c] = *(const bf16x8*)&Pl[w][g * 16 + lrow][c * 32 + quad * 8];
#pragma unroll
            for (int f = 0; f < 4; ++f) {
                const bf16x8 vf0 = *(const bf16x8*)&Vs[cbuf][f * 16 + lrow][ca];
                const bf16x8 vf1 = *(const bf16x8*)&Vs[cbuf][f * 16 + lrow][cb];
                O[0][f] = __builtin_amdgcn_mfma_f32_16x16x32_bf16(ap[0][0], vf0, O[0][f], 0, 0, 0);
                O[0][f] = __builtin_amdgcn_mfma_f32_16x16x32_bf16(ap[0][1], vf1, O[0][f], 0, 0, 0);
                O[1][f] = __builtin_amdgcn_mfma_f32_16x16x32_bf16(ap[1][0], vf0, O[1][f], 0, 0, 0);
                O[1][f] = __builtin_amdgcn_mfma_f32_16x16x32_bf16(ap[1][1], vf1, O[1][f], 0, 0, 0);
            }
        }

        cbuf = (cbuf == 2) ? 0 : cbuf + 1;
        sbuf = (sbuf == 2) ? 0 : sbuf + 1;
    }

    // final epilogue: half B
#pragma unroll
    for (int g = 0; g < 2; ++g) {
        float l = lsum[g];
        l += __shfl_xor(l, 16);
        l += __shfl_xor(l, 32);
        const float inv = 1.0f / l;
#pragma unroll
        for (int r = 0; r < 4; ++r) {
            const float invr = __shfl(inv, quad * 4 + r);
            const int q = qw + g * 16 + quad * 4 + r;
            const size_t base = ((size_t)b * Ss + q) * NXx + h * HDd;
#pragma unroll
            for (int f = 0; f < 4; ++f)
                about[base + f * 16 + lrow] = f2bf(O[g][f][r] * invr);
        }
    }
}

// ---------------- launch ----------------
extern "C" void kernel_launch(void* const* d_in, const int* in_sizes, int n_in,
                              void* d_out, int out_size, void* d_ws, size_t ws_size,
                              hipStream_t stream) {
    const float* x        = (const float*)d_in[0];
    const float* query    = (const float*)d_in[1];
    const float* c_attn_w = (const float*)d_in[2];
    const float* c_attn_b = (const float*)d_in[3];
    const float* c_proj_w = (const float*)d_in[4];
    const float* c_proj_b = (const float*)d_in[5];
    float* out = (float*)d_out;

    const size_t nTok = (size_t)Mm * NXx;          // 8388608
    char* ws = (char*)d_ws;
    unsigned short* xb    = (unsigned short*)ws;                 ws += nTok * 2;
    unsigned short* qb    = (unsigned short*)ws;                 ws += nTok * 2;
    unsigned short* Wt    = (unsigned short*)ws;                 ws += (size_t)3 * NXx * NXx * 2;  // [3072][1024]
    unsigned short* Pt    = (unsigned short*)ws;                 ws += (size_t)NXx * NXx * 2;      // [1024][1024]
    unsigned short* Qh    = (unsigned short*)ws;                 ws += nTok * 2;
    unsigned short* Kh    = (unsigned short*)ws;                 ws += nTok * 2;
    unsigned short* Vt    = (unsigned short*)ws;                 ws += nTok * 2;
    unsigned short* about = (unsigned short*)ws;                 ws += nTok * 2;
    if ((size_t)(ws - (char*)d_ws) > ws_size) return;

    // merged prep: casts + transposes
    prep<<<20480, 256, 0, stream>>>(x, query, c_attn_w, c_proj_w, xb, qb, Wt, Pt);

    // QKV: M=8192, N=3072, K=1024 — 256x128 tiles, BK=32, r4-verified config
    gemm256<<<768, 512, 0, stream>>>(xb, qb, Wt, c_attn_b, Qh, Kh, Vt);

    // causal flash attention (8-wave supertile pairs; VALU-diet inner loop)
    flash_attn<<<256, 512, 0, stream>>>(Qh, Kh, Vt, about);

    // output projection: M=8192, N=1024, K=1024 -> fp32 out (gemm128, measured-best)
    gemm128<<<dim3(8 * 64), 256, 0, stream>>>(about, nullptr, Pt, c_proj_b, NXx, 1,
                                              nullptr, nullptr, nullptr, out);
}